// Round 6
// baseline (344.142 us; speedup 1.0000x reference)
//
#include <hip/hip_runtime.h>
#include <hip/hip_bf16.h>
#include <math.h>

#define L_SEQ 8192
#define DM 1024
#define DI 2048
#define NH 32
#define HD 64
#define DS 128
#define CDIM 2304
#define DPROJ 4384
#define NPAD_IN 4608  // 36*128, zero-padded W_in rows
#define KSPLIT 16
#define OPROWS 2176   // 2048 Vs^T rows + 128 B^T rows

typedef short bf16x8 __attribute__((ext_vector_type(8)));
typedef float floatx4 __attribute__((ext_vector_type(4)));
typedef unsigned short u16x4 __attribute__((ext_vector_type(4)));
typedef unsigned short u16x8 __attribute__((ext_vector_type(8)));

#define AS1(p) ((const __attribute__((address_space(1))) void*)(p))
#define AS3(p) ((__attribute__((address_space(3))) void*)(p))

__device__ __forceinline__ float bf2f(unsigned short u) {
  union { unsigned int i; float f; } c; c.i = ((unsigned int)u) << 16; return c.f;
}
__device__ __forceinline__ unsigned short f2bf(float f) {
  return __bfloat16_as_ushort(__float2bfloat16(f));
}

// ---------------------------------------------------------------------------
// 128x128-tile TLP bf16 GEMM v2: BK=32, 3-slot LDS ring, 48 KB -> 3 blocks/CU.
// r5 post-mortem: 2 blocks/CU (64KB) gave 105->87us, VGPR only 52 of 128 ->
// occupancy was LDS-capped. This version: LDS 48KB (3 slots x (A 8KB + B 8KB)),
// __launch_bounds__(512,6) caps VGPR at 85 (need ~72: acc32+af16+b8+addr).
// C[m,n] = sum_k A[m,k]*B[n,k]. 512 thr = 8 waves (2M x 4N), per-wave 64x32
// out (acc[4][2] = 32 VGPR), NT = K/32 (NT>=2).
// NO swizzle: at BK=32 the LDS row stride is 64B, so a wave's b128 frag reads
// spread over banks at the 8-cycle bandwidth floor naturally (the XOR swizzle
// only repairs 128B-stride concentration). Staging dest + reads both linear.
// Each stage half (A or B) = exactly ONE global_load_lds instr (8KB=512x16B).
// Schedule per kt (slot s = kt%3), ONE barrier per kt:
//   reads: af[4]+b[2] (6 ds_read_b128 from slot s)
//   stage kt+2 -> slot (kt+2)%3 (2 gload)   [slot holds kt-1: all reads of
//     kt-1 completed before kt-1's trailing barrier -> landing is safe]
//   lgkm(0); prio1; 8 MFMA; prio0
//   vmcnt(2) [drains kt+1; kt+2 stays in flight] | vmcnt(0) at tail; barrier
// vmcnt ledger (2 instr per kt stage): prologue stages kt0(2)+kt1(2),
//   vmcnt(2) drains kt0, bar. Steady kt: outstanding kt+1(2)+kt+2(2);
//   vmcnt(2) drains kt+1 = exactly kt+1's inputs. Tail kt=NT-2: no stage,
//   vmcnt(0). kt=NT-1: no trailing wait.
// OMODE 0: bf16 out via LDS repack (32KB) after __syncthreads, Nstore guard.
// OMODE 1: f32 out, direct frag stores (16-lane 64B segments).
// ---------------------------------------------------------------------------
template <int OMODE>
__global__ __launch_bounds__(512, 6)
void gemm128_tlp3(const unsigned short* __restrict__ A, int lda,
                  const unsigned short* __restrict__ B, int ldb,
                  void* __restrict__ Cout, int ldc,
                  int K, int Nstore) {
  __shared__ __align__(16) char lds[49152];
  const int t = threadIdx.x;
  const int lane = t & 63;
  const int w = t >> 6;
  const int wm = w & 1, wn = w >> 1;
  const int fr = lane & 15, quad = lane >> 4;

  // bijective XCD swizzle: xcd owns a contiguous m-band, m-fastest within n
  int gx = gridDim.x, gy = gridDim.y;
  int linear = blockIdx.y * gx + blockIdx.x;
  int xcd = linear & 7, loc = linear >> 3;
  int mper = gy >> 3;                       // gy must be %8==0 (64 here)
  int mt = xcd * mper + loc % mper;
  int nt = loc / mper;
  const int m0 = mt << 7, n0 = nt << 7;
  const int NT = K >> 5;

  floatx4 acc[4][2];
#pragma unroll
  for (int i = 0; i < 4; ++i)
#pragma unroll
    for (int j = 0; j < 2; ++j) acc[i][j] = (floatx4){0.f, 0.f, 0.f, 0.f};
  bf16x8 af[4], bb[2];

  // ---- staging: one gload_lds instr per half (8KB = 512 lanes x 16B)
  auto stA = [&](int slot, int kt) {
    int o = t * 16;                          // byte off in 8KB A half
    int rloc = o >> 6, kb = o & 63;          // row (64B rows of 32 bf16), kbyte
    const unsigned short* src = A + (size_t)(m0 + rloc) * lda + (kt << 5) + (kb >> 1);
    __builtin_amdgcn_global_load_lds(AS1(src), AS3(lds + slot * 16384 + o), 16, 0, 0);
  };
  auto stB = [&](int slot, int kt) {
    int o = t * 16;
    int rloc = o >> 6, kb = o & 63;
    const unsigned short* src = B + (size_t)(n0 + rloc) * ldb + (kt << 5) + (kb >> 1);
    __builtin_amdgcn_global_load_lds(AS1(src), AS3(lds + slot * 16384 + 8192 + o), 16, 0, 0);
  };
  // ---- linear fragment reads (64B row stride -> bank-floor, no swizzle)
  auto rdA = [&](int slot, int mi) -> bf16x8 {
    int rloc = (wm << 6) | (mi << 4) | fr;
    return *(const bf16x8*)(lds + slot * 16384 + rloc * 64 + quad * 16);
  };
  auto rdB = [&](int slot, int ni) -> bf16x8 {
    int rloc = (wn << 5) | (ni << 4) | fr;
    return *(const bf16x8*)(lds + slot * 16384 + 8192 + rloc * 64 + quad * 16);
  };

  // ---- prologue: stage kt0 + kt1; vmcnt(2) -> kt0 landed
  stA(0, 0); stB(0, 0);
  if (NT > 1) {
    stA(1, 1); stB(1, 1);
    asm volatile("s_waitcnt vmcnt(2)" ::: "memory");
  } else {
    asm volatile("s_waitcnt vmcnt(0)" ::: "memory");
  }
  __builtin_amdgcn_s_barrier();

  int cur = 0;
  for (int kt = 0; kt < NT; ++kt) {
    const bool pf = (kt + 2 < NT);
    // reads from slot cur
#pragma unroll
    for (int mi = 0; mi < 4; ++mi) af[mi] = rdA(cur, mi);
    bb[0] = rdB(cur, 0); bb[1] = rdB(cur, 1);
    // stage kt+2 into slot (cur+2)%3 (holds kt-1; reads done 1 barrier back)
    if (pf) {
      int s2 = cur + 2; if (s2 >= 3) s2 -= 3;
      stA(s2, kt + 2); stB(s2, kt + 2);
    }
    asm volatile("s_waitcnt lgkmcnt(0)" ::: "memory");
    __builtin_amdgcn_s_setprio(1);
#pragma unroll
    for (int mi = 0; mi < 4; ++mi) {
      acc[mi][0] = __builtin_amdgcn_mfma_f32_16x16x32_bf16(af[mi], bb[0], acc[mi][0], 0, 0, 0);
      acc[mi][1] = __builtin_amdgcn_mfma_f32_16x16x32_bf16(af[mi], bb[1], acc[mi][1], 0, 0, 0);
    }
    __builtin_amdgcn_s_setprio(0);
    if (kt < NT - 1) {
      if (pf) asm volatile("s_waitcnt vmcnt(2)" ::: "memory");  // kt+1 landed
      else    asm volatile("s_waitcnt vmcnt(0)" ::: "memory");
      __builtin_amdgcn_s_barrier();
    }
    ++cur; if (cur == 3) cur = 0;
  }

  if (OMODE == 0) {
    // ---- epilogue: repack 128x128 bf16 through LDS, full-line stores
    __syncthreads();                   // all LDS reads done before reuse
    unsigned short* rp = (unsigned short*)lds;
    unsigned short* C = (unsigned short*)Cout;
    const int mb = wm * 64, nb = wn * 32;
#pragma unroll
    for (int mi = 0; mi < 4; ++mi)
#pragma unroll
      for (int ni = 0; ni < 2; ++ni)
#pragma unroll
        for (int r = 0; r < 4; ++r)
          rp[(mb + mi * 16 + quad * 4 + r) * 128 + nb + ni * 16 + fr] = f2bf(acc[mi][ni][r]);
    __syncthreads();
#pragma unroll
    for (int j = 0; j < 4; ++j) {
      int lin = j * 4096 + t * 8;
      int row = lin >> 7, col = lin & 127;
      int gcol = n0 + col;
      if (gcol < Nstore)
        *(u16x8*)&C[(size_t)(m0 + row) * ldc + gcol] = *(const u16x8*)&rp[lin];
    }
  } else {
    // ---- f32 direct frag stores: 16 consecutive lanes -> 64B segments
    float* Cf = (float*)Cout;
#pragma unroll
    for (int mi = 0; mi < 4; ++mi)
#pragma unroll
      for (int ni = 0; ni < 2; ++ni) {
        int gcol = n0 + wn * 32 + ni * 16 + fr;
        int grow = m0 + wm * 64 + mi * 16 + quad * 4;
#pragma unroll
        for (int r = 0; r < 4; ++r)
          if (gcol < Nstore)
            Cf[(size_t)(grow + r) * ldc + gcol] = acc[mi][ni][r];
      }
  }
}

// ---------------------------------------------------------------------------
// bf16 MFMA GEMM: C[m,n] = sum_k A[m,k]*B[n,k]  (K contiguous both operands)
// 128x128 tile, BK=32, 4 waves (2x2), 4x4 frags of 16x16x32 each.
// (Retained for MODE 1 (fused D-add, K=128) and MODE 2 (split-K).)
// ---------------------------------------------------------------------------
template <int MODE>
__global__ __launch_bounds__(256)
void gemm_bt_mfma(const unsigned short* __restrict__ A, int lda,
                  const unsigned short* __restrict__ B, int ldb,
                  void* __restrict__ Cout, int ldc,
                  int Kfull, int Nstore,
                  const unsigned short* __restrict__ xs,
                  const float* __restrict__ Dvec) {
  __shared__ __align__(16) char smem[17408];  // staging 16 KB; f32 repack 17 KB
  unsigned short* Asm = (unsigned short*)smem;
  unsigned short* Bsm = Asm + 128 * 32;
  const int t = threadIdx.x;

  int bx = blockIdx.x, by = blockIdx.y;
  if (MODE != 2) {
    int gx = gridDim.x;
    int linear = by * gx + bx;
    int xcd = linear & 7;
    int local = linear >> 3;
    by = xcd * 8 + (local & 7);
    bx = local >> 3;
  }
  const int m0 = by * 128;
  const int n0 = bx * 128;

  int kstart = 0, klen = Kfull;
  if (MODE == 2) { klen = Kfull / KSPLIT; kstart = blockIdx.z * klen; }
  const int wave = t >> 6, lane = t & 63;
  const int wm = (wave & 1) * 64;
  const int wn = (wave >> 1) * 64;
  const int fr = lane & 15;
  const int quad = lane >> 4;

  floatx4 acc[4][4];
#pragma unroll
  for (int i = 0; i < 4; ++i)
#pragma unroll
    for (int j = 0; j < 4; ++j) acc[i][j] = (floatx4){0.f, 0.f, 0.f, 0.f};

  for (int k0 = kstart; k0 < kstart + klen; k0 += 32) {
#pragma unroll
    for (int i = 0; i < 2; ++i) {
      int linear = i * 256 + t;          // 0..511
      int row = linear >> 2;             // 0..127
      int kq = (linear & 3) * 8;         // bf16 elem offset in K
      const unsigned short* ga = A + (size_t)(m0 + row) * lda + (k0 + kq);
      const unsigned short* gb = B + (size_t)(n0 + row) * ldb + (k0 + kq);
      __builtin_amdgcn_global_load_lds(AS1(ga), AS3(&Asm[linear * 8]), 16, 0, 0);
      __builtin_amdgcn_global_load_lds(AS1(gb), AS3(&Bsm[linear * 8]), 16, 0, 0);
    }
    __syncthreads();

    bf16x8 af[4], bfr[4];
#pragma unroll
    for (int i = 0; i < 4; ++i) {
      af[i]  = *(const bf16x8*)&Asm[(wm + i * 16 + fr) * 32 + quad * 8];
      bfr[i] = *(const bf16x8*)&Bsm[(wn + i * 16 + fr) * 32 + quad * 8];
    }
#pragma unroll
    for (int mi = 0; mi < 4; ++mi)
#pragma unroll
      for (int ni = 0; ni < 4; ++ni)
        acc[mi][ni] = __builtin_amdgcn_mfma_f32_16x16x32_bf16(
            af[mi], bfr[ni], acc[mi][ni], 0, 0, 0);
    __syncthreads();
  }

  // C/D frag layout: col = lane&15, row = (lane>>4)*4 + r  [m89-verified]
  const int lrbase = (wm ? 16 : 0) + quad * 4;
  if (MODE == 0 || MODE == 1) {
    unsigned short(*rp)[136] = (unsigned short(*)[136])smem;
    unsigned short* C = (unsigned short*)Cout;
#pragma unroll
    for (int mi = 0; mi < 4; ++mi) {
      __syncthreads();
#pragma unroll
      for (int ni = 0; ni < 4; ++ni)
#pragma unroll
        for (int r = 0; r < 4; ++r)
          rp[lrbase + r][wn + ni * 16 + fr] = f2bf(acc[mi][ni][r]);
      __syncthreads();
#pragma unroll
      for (int j = 0; j < 2; ++j) {
        int off = j * 2048 + t * 8;          // elem in 32x128 group
        int lr = off >> 7, c = off & 127;
        int grow = m0 + (lr >> 4) * 64 + mi * 16 + (lr & 15);
        int gcol = n0 + c;
        u16x8 v = *(const u16x8*)&rp[lr][c];
        if (MODE == 1) {
          u16x8 xv = *(const u16x8*)&xs[(size_t)grow * ldc + gcol];
          float Dh = Dvec[gcol >> 6];
          u16x8 o;
#pragma unroll
          for (int e = 0; e < 8; ++e) o[e] = f2bf(bf2f(v[e]) + Dh * bf2f(xv[e]));
          *(u16x8*)&C[(size_t)grow * ldc + gcol] = o;
        } else {
          if (gcol < Nstore) *(u16x8*)&C[(size_t)grow * ldc + gcol] = v;
        }
      }
    }
  } else {
    float(*rpf)[136] = (float(*)[136])smem;  // 32*136*4 = 17408 B
    float* C = (float*)Cout;
    if (MODE == 2) C += (size_t)blockIdx.z * DS * DI;
#pragma unroll
    for (int mi = 0; mi < 4; ++mi) {
      __syncthreads();
#pragma unroll
      for (int ni = 0; ni < 4; ++ni)
#pragma unroll
        for (int r = 0; r < 4; ++r)
          rpf[lrbase + r][wn + ni * 16 + fr] = acc[mi][ni][r];
      __syncthreads();
#pragma unroll
      for (int j = 0; j < 4; ++j) {
        int off = j * 1024 + t * 4;          // elem in 32x128 group
        int lr = off >> 7, c = off & 127;
        int grow = m0 + (lr >> 4) * 64 + mi * 16 + (lr & 15);
        int gcol = n0 + c;
        float4 v = *(const float4*)&rpf[lr][c];
        *(float4*)&C[(size_t)grow * ldc + gcol] = v;
      }
    }
  }
}

// ---------------------------------------------------------------------------
// One merged cast dispatch. Regions (in 256-thread blocks of 4-elem quads):
//   [0, 8192):        x       (8192x1024 f32 -> bf16)
//   [8192, 12800):    W_in    (4384x1024 -> 4608x1024 bf16, pad rows zero)
//   [12800, 14848):   W_out   (1024x2048 f32 -> bf16)
// ---------------------------------------------------------------------------
__global__ __launch_bounds__(256)
void cast_all_kernel(const float* __restrict__ x, const float* __restrict__ W_in,
                     const float* __restrict__ W_out,
                     unsigned short* __restrict__ x_bf16,
                     unsigned short* __restrict__ win_bf16,
                     unsigned short* __restrict__ wout_bf16) {
  int b = blockIdx.x;
  int t = threadIdx.x;
  u16x4 o = (u16x4){0, 0, 0, 0};
  if (b < 8192) {
    size_t i4 = ((size_t)b * 256 + t) * 4;
    float4 v = *(const float4*)(x + i4);
    o.x = f2bf(v.x); o.y = f2bf(v.y); o.z = f2bf(v.z); o.w = f2bf(v.w);
    *(u16x4*)(x_bf16 + i4) = o;
  } else if (b < 12800) {
    size_t i4 = ((size_t)(b - 8192) * 256 + t) * 4;  // over 4608*1024
    int row = (int)(i4 >> 10);
    if (row < DPROJ) {
      float4 v = *(const float4*)(W_in + i4);
      o.x = f2bf(v.x); o.y = f2bf(v.y); o.z = f2bf(v.z); o.w = f2bf(v.w);
    }
    *(u16x4*)(win_bf16 + i4) = o;
  } else {
    size_t i4 = ((size_t)(b - 12800) * 256 + t) * 4;
    float4 v = *(const float4*)(W_out + i4);
    o.x = f2bf(v.x); o.y = f2bf(v.y); o.z = f2bf(v.z); o.w = f2bf(v.w);
    *(u16x4*)(wout_bf16 + i4) = o;
  }
}

// ---------------------------------------------------------------------------
// s[l,h] = dt * exp(-dt*exp(A_log[h])),  dt = softplus(zxb[l,4352+h]+dt_bias[h])
// ---------------------------------------------------------------------------
__global__ __launch_bounds__(256)
void dt_kernel(const unsigned short* __restrict__ zxb, const float* __restrict__ dt_bias,
               const float* __restrict__ A_log, float* __restrict__ s_out) {
  int idx = blockIdx.x * 256 + threadIdx.x;  // l*32 + h
  int l = idx >> 5, h = idx & 31;
  float v = bf2f(zxb[(size_t)l * DPROJ + (DI + CDIM) + h]) + dt_bias[h];
  float d = (v > 20.f) ? v : log1pf(expf(v));
  s_out[idx] = d * expf(-d * expf(A_log[h]));
}

// ---------------------------------------------------------------------------
// Fused conv+silu+transpose. Block = 64 channels x 64 l, 256 threads.
// ---------------------------------------------------------------------------
__global__ __launch_bounds__(256)
void conv_fused_kernel(const unsigned short* __restrict__ zxb,
                       const float* __restrict__ Wc,
                       const float* __restrict__ bc,
                       const float* __restrict__ svec,
                       unsigned short* __restrict__ xs,
                       unsigned short* __restrict__ cb,
                       unsigned short* __restrict__ OpT) {
  __shared__ unsigned short zt[67][66];
  __shared__ unsigned short ot[64][66];
  __shared__ float sl[64];
  const int c0 = blockIdx.x * 64;
  const int l0 = blockIdx.y * 64;
  const int t = threadIdx.x;
  for (int idx = t; idx < 67 * 16; idx += 256) {
    int row = idx >> 4;
    int colq = (idx & 15) * 4;
    int gl = l0 - 1 + row;
    u16x4 v = (u16x4){0, 0, 0, 0};
    if (gl >= 0 && gl < L_SEQ)
      v = *(const u16x4*)&zxb[(size_t)gl * DPROJ + DI + c0 + colq];
    *(u16x4*)&zt[row][colq] = v;
  }
  const bool isX = (c0 < DI);
  const bool isC = (c0 >= DI + DS);
  if (isX && t < 64) sl[t] = svec[(size_t)(l0 + t) * NH + (c0 >> 6)];
  const int c = t & 63;
  const int gc = c0 + c;
  const float4 wv = *(const float4*)&Wc[gc * 4];
  const float bias = bc[gc];
  const int lq = (t >> 6) * 16;
  __syncthreads();
#pragma unroll
  for (int i = 0; i < 16; ++i) {
    int ll = lq + i;
    float sacc = bias + bf2f(zt[ll][c]) * wv.x + bf2f(zt[ll + 1][c]) * wv.y +
                 bf2f(zt[ll + 2][c]) * wv.z + bf2f(zt[ll + 3][c]) * wv.w;
    float v = sacc / (1.f + expf(-sacc));
    int gl = l0 + ll;
    if (isC) {
      cb[(size_t)gl * DS + (gc - (DI + DS))] = f2bf(v);
    } else if (isX) {
      xs[(size_t)gl * DI + gc] = f2bf(v);
      ot[c][ll] = f2bf(v * sl[ll]);
    } else {
      ot[c][ll] = f2bf(v);
    }
  }
  if (!isC) {
    __syncthreads();
#pragma unroll
    for (int j = 0; j < 4; ++j) {
      int linear = j * 1024 + t * 4;
      int rr = linear >> 6;
      int lc = linear & 63;
      *(u16x4*)&OpT[(size_t)(c0 + rr) * L_SEQ + l0 + lc] = *(const u16x4*)&ot[rr][lc];
    }
  }
}

// ---------------------------------------------------------------------------
// Ht[p][n] = bf16( sum_z Ppart[z][n][p] )
// ---------------------------------------------------------------------------
__global__ __launch_bounds__(256)
void h_reduce_t_kernel(const float* __restrict__ P, unsigned short* __restrict__ Ht) {
  __shared__ float tile[32][65];
  const int bid = blockIdx.x;
  const int pt = bid & 31, ng = bid >> 5;
  const int t = threadIdx.x;
#pragma unroll
  for (int i = 0; i < 8; ++i) {
    int nl = i * 4 + (t >> 6);
    int n = ng * 32 + nl;
    int p = pt * 64 + (t & 63);
    float acc = 0.f;
#pragma unroll
    for (int z = 0; z < KSPLIT; ++z)
      acc += P[(size_t)z * (DS * DI) + (size_t)n * DI + p];
    tile[nl][t & 63] = acc;
  }
  __syncthreads();
#pragma unroll
  for (int j = 0; j < 8; ++j) {
    int linear = j * 256 + t;
    int pl = linear >> 5, nl = linear & 31;
    Ht[(size_t)(pt * 64 + pl) * DS + ng * 32 + nl] = f2bf(tile[nl][pl]);
  }
}

// ---------------------------------------------------------------------------
// LayerNorm over 2048 (bf16 y) + z-gate (bf16 z); bf16 yz into zxb [2048,4096)
// ---------------------------------------------------------------------------
__global__ __launch_bounds__(256)
void ln_mul_kernel(const unsigned short* __restrict__ ybuf, unsigned short* __restrict__ zxb,
                   const float* __restrict__ ln_w, const float* __restrict__ ln_b) {
  int l = blockIdx.x;
  int t = threadIdx.x;
  int c0 = t * 8;
  u16x8 yv = *(const u16x8*)&ybuf[(size_t)l * DI + c0];
  float vals[8];
  float s = 0.f, sq = 0.f;
#pragma unroll
  for (int i = 0; i < 8; ++i) {
    float v = bf2f(yv[i]);
    vals[i] = v;
    s += v;
    sq += v * v;
  }
#pragma unroll
  for (int off = 32; off > 0; off >>= 1) {
    s += __shfl_down(s, off, 64);
    sq += __shfl_down(sq, off, 64);
  }
  __shared__ float red[10];
  int wave = t >> 6, lane = t & 63;
  if (lane == 0) { red[wave] = s; red[4 + wave] = sq; }
  __syncthreads();
  if (t == 0) {
    float S = red[0] + red[1] + red[2] + red[3];
    float SQ = red[4] + red[5] + red[6] + red[7];
    float mu = S / (float)DI;
    red[8] = mu;
    red[9] = rsqrtf(SQ / (float)DI - mu * mu + 1e-5f);
  }
  __syncthreads();
  float mu = red[8], rstd = red[9];
  unsigned short* zrow = zxb + (size_t)l * DPROJ;
  u16x8 zv = *(const u16x8*)&zrow[c0];
  float4 w0 = *(const float4*)&ln_w[c0], w1 = *(const float4*)&ln_w[c0 + 4];
  float4 b0 = *(const float4*)&ln_b[c0], b1 = *(const float4*)&ln_b[c0 + 4];
  float w[8] = {w0.x, w0.y, w0.z, w0.w, w1.x, w1.y, w1.z, w1.w};
  float b[8] = {b0.x, b0.y, b0.z, b0.w, b1.x, b1.y, b1.z, b1.w};
  u16x8 o;
#pragma unroll
  for (int i = 0; i < 8; ++i) {
    float v = (vals[i] - mu) * rstd * w[i] + b[i];
    o[i] = f2bf(v * bf2f(zv[i]));
  }
  *(u16x8*)&zrow[DI + c0] = o;
}

// ---------------------------------------------------------------------------
extern "C" void kernel_launch(void* const* d_in, const int* in_sizes, int n_in,
                              void* d_out, int out_size, void* d_ws, size_t ws_size,
                              hipStream_t stream) {
  const float* x       = (const float*)d_in[0];
  const float* W_in    = (const float*)d_in[1];
  const float* W_conv  = (const float*)d_in[2];
  const float* b_conv  = (const float*)d_in[3];
  const float* dt_bias = (const float*)d_in[4];
  const float* A_log   = (const float*)d_in[5];
  const float* D_param = (const float*)d_in[6];
  const float* ln_w    = (const float*)d_in[7];
  const float* ln_b    = (const float*)d_in[8];
  const float* W_out   = (const float*)d_in[9];
  float* out = (float*)d_out;

  // ---- workspace layout ----
  unsigned short* zxb = (unsigned short*)d_ws;           // L*4384 bf16
  unsigned short* xs   = zxb + (size_t)L_SEQ * DPROJ;    // L*2048 bf16
  unsigned short* cb   = xs + (size_t)L_SEQ * DI;        // L*128 bf16
  float* svec = (float*)(cb + (size_t)L_SEQ * DS);       // L*32 f32
  unsigned short* OpT = (unsigned short*)(svec + (size_t)L_SEQ * NH);  // 2176*8192 bf16
  float* Ppart = (float*)(OpT + (size_t)OPROWS * L_SEQ); // KSPLIT*128*2048 f32
  unsigned short* Ht = (unsigned short*)(Ppart + (size_t)KSPLIT * DS * DI);  // 2048*128
  unsigned short* wout_bf16 = Ht + (size_t)DI * DS;      // 1024*2048 bf16
  // aliases in OpT's dead windows:
  unsigned short* x_bf16   = OpT;                        // casts..GEMM1 (16 MB)
  unsigned short* win_bf16 = OpT + (size_t)L_SEQ * DM;   // casts..GEMM1 (9.4 MB)
  unsigned short* ybuf     = OpT;                        // Y-GEMM..ln_mul (33.5 MB)

  // 0) all casts in one dispatch
  cast_all_kernel<<<14848, 256, 0, stream>>>(x, W_in, W_out, x_bf16, win_bf16,
                                             wout_bf16);

  // 1) zxb = bf16( x @ W_in^T )  (M=8192, N=4608 pad, K=1024)
  //    128x128 TLP3, 48 KB LDS -> 3 blocks/CU; grid 36x64 = 2304 = 3 rounds
  gemm128_tlp3<0><<<dim3(NPAD_IN / 128, L_SEQ / 128), 512, 0, stream>>>(
      x_bf16, DM, win_bf16, DM, zxb, DPROJ, DM, DPROJ);

  // 2) s = a*dt
  dt_kernel<<<(L_SEQ * NH) / 256, 256, 0, stream>>>(zxb, dt_bias, A_log, svec);

  // 3) conv + silu + transpose-pack (clobbers x_bf16/win_bf16 — dead)
  conv_fused_kernel<<<dim3(CDIM / 64, L_SEQ / 64), 256, 0, stream>>>(
      zxb, W_conv, b_conv, svec, xs, cb, OpT);

  // 4) Hcat = B^T @ Vs : M=128, N=2048, K=8192, split-K=16 (256 blocks, f32 out)
  gemm_bt_mfma<2><<<dim3(DI / 128, 1, KSPLIT), 256, 0, stream>>>(
      OpT + (size_t)DI * L_SEQ, L_SEQ, OpT, L_SEQ, Ppart, DI, L_SEQ, DI,
      nullptr, nullptr);

  // 5) reduce partials + transpose -> Ht (2048 x 128 bf16)
  h_reduce_t_kernel<<<128, 256, 0, stream>>>(Ppart, Ht);

  // 6) y = C @ Hcat + D*x_ssm : M=8192, N=2048, K=128, bf16 repacked out
  gemm_bt_mfma<1><<<dim3(DI / 128, L_SEQ / 128), 256, 0, stream>>>(
      cb, DS, Ht, DS, ybuf, DI, DS, DI, xs, D_param);

  // 7) LN + z-gate -> bf16 yz into zxb cols [2048,4096)
  ln_mul_kernel<<<L_SEQ, 256, 0, stream>>>(ybuf, zxb, ln_w, ln_b);

  // 8) out = yz @ W_out^T : M=8192, N=1024, K=2048
  //    128x128 TLP3 f32 out: grid 8 x 64 = 512 blocks
  gemm128_tlp3<1><<<dim3(DM / 128, L_SEQ / 128), 512, 0, stream>>>(
      zxb + DI, DPROJ, wout_bf16, DI, out, DM, DI, DM);
}

// Round 7
// 340.119 us; speedup vs baseline: 1.0118x; 1.0118x over previous
//
#include <hip/hip_runtime.h>
#include <hip/hip_bf16.h>
#include <math.h>

#define L_SEQ 8192
#define DM 1024
#define DI 2048
#define NH 32
#define HD 64
#define DS 128
#define CDIM 2304
#define DPROJ 4384
#define NPAD_IN 4608  // 36*128, zero-padded W_in rows
#define KSPLIT 16
#define OPROWS 2176   // 2048 Vs^T rows + 128 B^T rows

typedef short bf16x8 __attribute__((ext_vector_type(8)));
typedef float floatx4 __attribute__((ext_vector_type(4)));
typedef unsigned short u16x4 __attribute__((ext_vector_type(4)));
typedef unsigned short u16x8 __attribute__((ext_vector_type(8)));

#define AS1(p) ((const __attribute__((address_space(1))) void*)(p))
#define AS3(p) ((__attribute__((address_space(3))) void*)(p))

__device__ __forceinline__ float bf2f(unsigned short u) {
  union { unsigned int i; float f; } c; c.i = ((unsigned int)u) << 16; return c.f;
}
__device__ __forceinline__ unsigned short f2bf(float f) {
  return __bfloat16_as_ushort(__float2bfloat16(f));
}

// ---------------------------------------------------------------------------
// 128x128-tile TLP bf16 GEMM v3: BK=32, 3-slot ring (48 KB -> 3 blocks/CU)
// WITH the r5-proven XOR swizzle via a paired-row LDS layout.
// r6 post-mortem: 64B LDS rows put consecutive frag rows at banks {0,16} only
// -> 8-way conflict (SQ_LDS_BANK_CONFLICT 1.2M->15.3M), MfmaUtil 33%.
// Fix: store each 128x32 half-tile as 64 rows x 128B, where LDS row r holds
// m-rows r (bytes [0,64)) and r+64 (bytes [64,128)). Row stride = 128 B = 32
// banks, so the involution byte ^= ((byte>>7)&7)<<4 works exactly as in r5:
// staging = linear dest + inverse-swizzled global source (bijective),
// frag read chunk = ((half<<2)|quad) ^ (fr&7) -> 16 lanes over 8 slots =
// free 2-way aliasing (m136). K-slice check: deswizzled chunk -> kb =
// quad*16..+16 = mfma K elems quad*8..+8. [verified by hand, r7]
// C[m,n] = sum_k A[m,k]*B[n,k]. 512 thr = 8 waves (2M x 4N), per-wave 64x32
// out (acc[4][2] = 32 VGPR), NT = K/32 (NT>=2). launch_bounds (512,6).
// Schedule per kt (slot s = kt%3), ONE barrier per kt:
//   6 ds_read_b128 from slot s; stage kt+2 -> slot (s+2)%3 (2 gload; that
//   slot holds kt-1, whose reads finished 1 barrier back); lgkm(0); prio1;
//   8 MFMA; prio0; vmcnt(2) [drains kt+1] | vmcnt(0) at tail; barrier.
// vmcnt ledger (2 gload per kt): prologue kt0(2)+kt1(2), vmcnt(2)=kt0, bar.
//   Steady: outstanding kt+1(2)+kt+2(2); vmcnt(2) drains kt+1. Tail kt=NT-2:
//   no stage, vmcnt(0). kt=NT-1: no trailing wait.
// OMODE 0: bf16 out via LDS repack (32KB) after __syncthreads, Nstore guard.
// OMODE 1: f32 out, direct frag stores (16-lane 64B segments).
// ---------------------------------------------------------------------------
template <int OMODE>
__global__ __launch_bounds__(512, 6)
void gemm128_tlp3(const unsigned short* __restrict__ A, int lda,
                  const unsigned short* __restrict__ B, int ldb,
                  void* __restrict__ Cout, int ldc,
                  int K, int Nstore) {
  __shared__ __align__(16) char lds[49152];
  const int t = threadIdx.x;
  const int lane = t & 63;
  const int w = t >> 6;
  const int wm = w & 1, wn = w >> 1;
  const int fr = lane & 15, quad = lane >> 4;

  // bijective XCD swizzle: xcd owns a contiguous m-band, m-fastest within n
  int gx = gridDim.x, gy = gridDim.y;
  int linear = blockIdx.y * gx + blockIdx.x;
  int xcd = linear & 7, loc = linear >> 3;
  int mper = gy >> 3;                       // gy must be %8==0 (64 here)
  int mt = xcd * mper + loc % mper;
  int nt = loc / mper;
  const int m0 = mt << 7, n0 = nt << 7;
  const int NT = K >> 5;

  floatx4 acc[4][2];
#pragma unroll
  for (int i = 0; i < 4; ++i)
#pragma unroll
    for (int j = 0; j < 2; ++j) acc[i][j] = (floatx4){0.f, 0.f, 0.f, 0.f};
  bf16x8 af[4], bb[2];

  // ---- staging: linear LDS dest; source = deswizzled (R, kb) for dest o.
  // dest o in [0,8192): os = o ^ swz; LDS row r128 = os>>7; half = (os>>6)&1;
  // kb = os&63; m-row R = half*64 + r128.
  auto stA = [&](int slot, int kt) {
    int o = t * 16;
    int os = o ^ (((o >> 7) & 7) << 4);
    int r128 = os >> 7, half = (os >> 6) & 1, kb = os & 63;
    int R = (half << 6) | r128;
    const unsigned short* src = A + (size_t)(m0 + R) * lda + (kt << 5) + (kb >> 1);
    __builtin_amdgcn_global_load_lds(AS1(src), AS3(lds + slot * 16384 + o), 16, 0, 0);
  };
  auto stB = [&](int slot, int kt) {
    int o = t * 16;
    int os = o ^ (((o >> 7) & 7) << 4);
    int r128 = os >> 7, half = (os >> 6) & 1, kb = os & 63;
    int R = (half << 6) | r128;
    const unsigned short* src = B + (size_t)(n0 + R) * ldb + (kt << 5) + (kb >> 1);
    __builtin_amdgcn_global_load_lds(AS1(src), AS3(lds + slot * 16384 + 8192 + o), 16, 0, 0);
  };
  // ---- swizzled fragment reads: m-row R -> LDS row R&63, half R>>6;
  // chunk = ((half<<2)|quad) ^ (fr&7)  (16B chunks; r128&7 == fr&7)
  auto rdA = [&](int slot, int mi) -> bf16x8 {
    int r128 = (mi << 4) | fr;               // R&63 (wm is the half bit)
    int chunk = ((wm << 2) | quad) ^ (fr & 7);
    return *(const bf16x8*)(lds + slot * 16384 + r128 * 128 + chunk * 16);
  };
  auto rdB = [&](int slot, int ni) -> bf16x8 {
    int R = (wn << 5) | (ni << 4) | fr;
    int r128 = R & 63, half = R >> 6;
    int chunk = ((half << 2) | quad) ^ (fr & 7);
    return *(const bf16x8*)(lds + slot * 16384 + 8192 + r128 * 128 + chunk * 16);
  };

  // ---- prologue: stage kt0 + kt1; vmcnt(2) -> kt0 landed
  stA(0, 0); stB(0, 0);
  if (NT > 1) {
    stA(1, 1); stB(1, 1);
    asm volatile("s_waitcnt vmcnt(2)" ::: "memory");
  } else {
    asm volatile("s_waitcnt vmcnt(0)" ::: "memory");
  }
  __builtin_amdgcn_s_barrier();

  int cur = 0;
  for (int kt = 0; kt < NT; ++kt) {
    const bool pf = (kt + 2 < NT);
    // reads from slot cur
#pragma unroll
    for (int mi = 0; mi < 4; ++mi) af[mi] = rdA(cur, mi);
    bb[0] = rdB(cur, 0); bb[1] = rdB(cur, 1);
    // stage kt+2 into slot (cur+2)%3 (holds kt-1; reads done 1 barrier back)
    if (pf) {
      int s2 = cur + 2; if (s2 >= 3) s2 -= 3;
      stA(s2, kt + 2); stB(s2, kt + 2);
    }
    asm volatile("s_waitcnt lgkmcnt(0)" ::: "memory");
    __builtin_amdgcn_s_setprio(1);
#pragma unroll
    for (int mi = 0; mi < 4; ++mi) {
      acc[mi][0] = __builtin_amdgcn_mfma_f32_16x16x32_bf16(af[mi], bb[0], acc[mi][0], 0, 0, 0);
      acc[mi][1] = __builtin_amdgcn_mfma_f32_16x16x32_bf16(af[mi], bb[1], acc[mi][1], 0, 0, 0);
    }
    __builtin_amdgcn_s_setprio(0);
    if (kt < NT - 1) {
      if (pf) asm volatile("s_waitcnt vmcnt(2)" ::: "memory");  // kt+1 landed
      else    asm volatile("s_waitcnt vmcnt(0)" ::: "memory");
      __builtin_amdgcn_s_barrier();
    }
    ++cur; if (cur == 3) cur = 0;
  }

  if (OMODE == 0) {
    // ---- epilogue: repack 128x128 bf16 through LDS, full-line stores
    __syncthreads();                   // all LDS reads done before reuse
    unsigned short* rp = (unsigned short*)lds;
    unsigned short* C = (unsigned short*)Cout;
    const int mb = wm * 64, nb = wn * 32;
#pragma unroll
    for (int mi = 0; mi < 4; ++mi)
#pragma unroll
      for (int ni = 0; ni < 2; ++ni)
#pragma unroll
        for (int r = 0; r < 4; ++r)
          rp[(mb + mi * 16 + quad * 4 + r) * 128 + nb + ni * 16 + fr] = f2bf(acc[mi][ni][r]);
    __syncthreads();
#pragma unroll
    for (int j = 0; j < 4; ++j) {
      int lin = j * 4096 + t * 8;
      int row = lin >> 7, col = lin & 127;
      int gcol = n0 + col;
      if (gcol < Nstore)
        *(u16x8*)&C[(size_t)(m0 + row) * ldc + gcol] = *(const u16x8*)&rp[lin];
    }
  } else {
    // ---- f32 direct frag stores: 16 consecutive lanes -> 64B segments
    float* Cf = (float*)Cout;
#pragma unroll
    for (int mi = 0; mi < 4; ++mi)
#pragma unroll
      for (int ni = 0; ni < 2; ++ni) {
        int gcol = n0 + wn * 32 + ni * 16 + fr;
        int grow = m0 + wm * 64 + mi * 16 + quad * 4;
#pragma unroll
        for (int r = 0; r < 4; ++r)
          if (gcol < Nstore)
            Cf[(size_t)(grow + r) * ldc + gcol] = acc[mi][ni][r];
      }
  }
}

// ---------------------------------------------------------------------------
// bf16 MFMA GEMM: C[m,n] = sum_k A[m,k]*B[n,k]  (K contiguous both operands)
// 128x128 tile, BK=32, 4 waves (2x2), 4x4 frags of 16x16x32 each.
// (Retained for MODE 1 (fused D-add, K=128) and MODE 2 (split-K).)
// ---------------------------------------------------------------------------
template <int MODE>
__global__ __launch_bounds__(256)
void gemm_bt_mfma(const unsigned short* __restrict__ A, int lda,
                  const unsigned short* __restrict__ B, int ldb,
                  void* __restrict__ Cout, int ldc,
                  int Kfull, int Nstore,
                  const unsigned short* __restrict__ xs,
                  const float* __restrict__ Dvec) {
  __shared__ __align__(16) char smem[17408];  // staging 16 KB; f32 repack 17 KB
  unsigned short* Asm = (unsigned short*)smem;
  unsigned short* Bsm = Asm + 128 * 32;
  const int t = threadIdx.x;

  int bx = blockIdx.x, by = blockIdx.y;
  if (MODE != 2) {
    int gx = gridDim.x;
    int linear = by * gx + bx;
    int xcd = linear & 7;
    int local = linear >> 3;
    by = xcd * 8 + (local & 7);
    bx = local >> 3;
  }
  const int m0 = by * 128;
  const int n0 = bx * 128;

  int kstart = 0, klen = Kfull;
  if (MODE == 2) { klen = Kfull / KSPLIT; kstart = blockIdx.z * klen; }
  const int wave = t >> 6, lane = t & 63;
  const int wm = (wave & 1) * 64;
  const int wn = (wave >> 1) * 64;
  const int fr = lane & 15;
  const int quad = lane >> 4;

  floatx4 acc[4][4];
#pragma unroll
  for (int i = 0; i < 4; ++i)
#pragma unroll
    for (int j = 0; j < 4; ++j) acc[i][j] = (floatx4){0.f, 0.f, 0.f, 0.f};

  for (int k0 = kstart; k0 < kstart + klen; k0 += 32) {
#pragma unroll
    for (int i = 0; i < 2; ++i) {
      int linear = i * 256 + t;          // 0..511
      int row = linear >> 2;             // 0..127
      int kq = (linear & 3) * 8;         // bf16 elem offset in K
      const unsigned short* ga = A + (size_t)(m0 + row) * lda + (k0 + kq);
      const unsigned short* gb = B + (size_t)(n0 + row) * ldb + (k0 + kq);
      __builtin_amdgcn_global_load_lds(AS1(ga), AS3(&Asm[linear * 8]), 16, 0, 0);
      __builtin_amdgcn_global_load_lds(AS1(gb), AS3(&Bsm[linear * 8]), 16, 0, 0);
    }
    __syncthreads();

    bf16x8 af[4], bfr[4];
#pragma unroll
    for (int i = 0; i < 4; ++i) {
      af[i]  = *(const bf16x8*)&Asm[(wm + i * 16 + fr) * 32 + quad * 8];
      bfr[i] = *(const bf16x8*)&Bsm[(wn + i * 16 + fr) * 32 + quad * 8];
    }
#pragma unroll
    for (int mi = 0; mi < 4; ++mi)
#pragma unroll
      for (int ni = 0; ni < 4; ++ni)
        acc[mi][ni] = __builtin_amdgcn_mfma_f32_16x16x32_bf16(
            af[mi], bfr[ni], acc[mi][ni], 0, 0, 0);
    __syncthreads();
  }

  // C/D frag layout: col = lane&15, row = (lane>>4)*4 + r  [m89-verified]
  const int lrbase = (wm ? 16 : 0) + quad * 4;
  if (MODE == 0 || MODE == 1) {
    unsigned short(*rp)[136] = (unsigned short(*)[136])smem;
    unsigned short* C = (unsigned short*)Cout;
#pragma unroll
    for (int mi = 0; mi < 4; ++mi) {
      __syncthreads();
#pragma unroll
      for (int ni = 0; ni < 4; ++ni)
#pragma unroll
        for (int r = 0; r < 4; ++r)
          rp[lrbase + r][wn + ni * 16 + fr] = f2bf(acc[mi][ni][r]);
      __syncthreads();
#pragma unroll
      for (int j = 0; j < 2; ++j) {
        int off = j * 2048 + t * 8;          // elem in 32x128 group
        int lr = off >> 7, c = off & 127;
        int grow = m0 + (lr >> 4) * 64 + mi * 16 + (lr & 15);
        int gcol = n0 + c;
        u16x8 v = *(const u16x8*)&rp[lr][c];
        if (MODE == 1) {
          u16x8 xv = *(const u16x8*)&xs[(size_t)grow * ldc + gcol];
          float Dh = Dvec[gcol >> 6];
          u16x8 o;
#pragma unroll
          for (int e = 0; e < 8; ++e) o[e] = f2bf(bf2f(v[e]) + Dh * bf2f(xv[e]));
          *(u16x8*)&C[(size_t)grow * ldc + gcol] = o;
        } else {
          if (gcol < Nstore) *(u16x8*)&C[(size_t)grow * ldc + gcol] = v;
        }
      }
    }
  } else {
    float(*rpf)[136] = (float(*)[136])smem;  // 32*136*4 = 17408 B
    float* C = (float*)Cout;
    if (MODE == 2) C += (size_t)blockIdx.z * DS * DI;
#pragma unroll
    for (int mi = 0; mi < 4; ++mi) {
      __syncthreads();
#pragma unroll
      for (int ni = 0; ni < 4; ++ni)
#pragma unroll
        for (int r = 0; r < 4; ++r)
          rpf[lrbase + r][wn + ni * 16 + fr] = acc[mi][ni][r];
      __syncthreads();
#pragma unroll
      for (int j = 0; j < 4; ++j) {
        int off = j * 1024 + t * 4;          // elem in 32x128 group
        int lr = off >> 7, c = off & 127;
        int grow = m0 + (lr >> 4) * 64 + mi * 16 + (lr & 15);
        int gcol = n0 + c;
        float4 v = *(const float4*)&rpf[lr][c];
        *(float4*)&C[(size_t)grow * ldc + gcol] = v;
      }
    }
  }
}

// ---------------------------------------------------------------------------
// One merged cast dispatch. Regions (in 256-thread blocks of 4-elem quads):
//   [0, 8192):        x       (8192x1024 f32 -> bf16)
//   [8192, 12800):    W_in    (4384x1024 -> 4608x1024 bf16, pad rows zero)
//   [12800, 14848):   W_out   (1024x2048 f32 -> bf16)
// ---------------------------------------------------------------------------
__global__ __launch_bounds__(256)
void cast_all_kernel(const float* __restrict__ x, const float* __restrict__ W_in,
                     const float* __restrict__ W_out,
                     unsigned short* __restrict__ x_bf16,
                     unsigned short* __restrict__ win_bf16,
                     unsigned short* __restrict__ wout_bf16) {
  int b = blockIdx.x;
  int t = threadIdx.x;
  u16x4 o = (u16x4){0, 0, 0, 0};
  if (b < 8192) {
    size_t i4 = ((size_t)b * 256 + t) * 4;
    float4 v = *(const float4*)(x + i4);
    o.x = f2bf(v.x); o.y = f2bf(v.y); o.z = f2bf(v.z); o.w = f2bf(v.w);
    *(u16x4*)(x_bf16 + i4) = o;
  } else if (b < 12800) {
    size_t i4 = ((size_t)(b - 8192) * 256 + t) * 4;  // over 4608*1024
    int row = (int)(i4 >> 10);
    if (row < DPROJ) {
      float4 v = *(const float4*)(W_in + i4);
      o.x = f2bf(v.x); o.y = f2bf(v.y); o.z = f2bf(v.z); o.w = f2bf(v.w);
    }
    *(u16x4*)(win_bf16 + i4) = o;
  } else {
    size_t i4 = ((size_t)(b - 12800) * 256 + t) * 4;
    float4 v = *(const float4*)(W_out + i4);
    o.x = f2bf(v.x); o.y = f2bf(v.y); o.z = f2bf(v.z); o.w = f2bf(v.w);
    *(u16x4*)(wout_bf16 + i4) = o;
  }
}

// ---------------------------------------------------------------------------
// s[l,h] = dt * exp(-dt*exp(A_log[h])),  dt = softplus(zxb[l,4352+h]+dt_bias[h])
// ---------------------------------------------------------------------------
__global__ __launch_bounds__(256)
void dt_kernel(const unsigned short* __restrict__ zxb, const float* __restrict__ dt_bias,
               const float* __restrict__ A_log, float* __restrict__ s_out) {
  int idx = blockIdx.x * 256 + threadIdx.x;  // l*32 + h
  int l = idx >> 5, h = idx & 31;
  float v = bf2f(zxb[(size_t)l * DPROJ + (DI + CDIM) + h]) + dt_bias[h];
  float d = (v > 20.f) ? v : log1pf(expf(v));
  s_out[idx] = d * expf(-d * expf(A_log[h]));
}

// ---------------------------------------------------------------------------
// Fused conv+silu+transpose. Block = 64 channels x 64 l, 256 threads.
// ---------------------------------------------------------------------------
__global__ __launch_bounds__(256)
void conv_fused_kernel(const unsigned short* __restrict__ zxb,
                       const float* __restrict__ Wc,
                       const float* __restrict__ bc,
                       const float* __restrict__ svec,
                       unsigned short* __restrict__ xs,
                       unsigned short* __restrict__ cb,
                       unsigned short* __restrict__ OpT) {
  __shared__ unsigned short zt[67][66];
  __shared__ unsigned short ot[64][66];
  __shared__ float sl[64];
  const int c0 = blockIdx.x * 64;
  const int l0 = blockIdx.y * 64;
  const int t = threadIdx.x;
  for (int idx = t; idx < 67 * 16; idx += 256) {
    int row = idx >> 4;
    int colq = (idx & 15) * 4;
    int gl = l0 - 1 + row;
    u16x4 v = (u16x4){0, 0, 0, 0};
    if (gl >= 0 && gl < L_SEQ)
      v = *(const u16x4*)&zxb[(size_t)gl * DPROJ + DI + c0 + colq];
    *(u16x4*)&zt[row][colq] = v;
  }
  const bool isX = (c0 < DI);
  const bool isC = (c0 >= DI + DS);
  if (isX && t < 64) sl[t] = svec[(size_t)(l0 + t) * NH + (c0 >> 6)];
  const int c = t & 63;
  const int gc = c0 + c;
  const float4 wv = *(const float4*)&Wc[gc * 4];
  const float bias = bc[gc];
  const int lq = (t >> 6) * 16;
  __syncthreads();
#pragma unroll
  for (int i = 0; i < 16; ++i) {
    int ll = lq + i;
    float sacc = bias + bf2f(zt[ll][c]) * wv.x + bf2f(zt[ll + 1][c]) * wv.y +
                 bf2f(zt[ll + 2][c]) * wv.z + bf2f(zt[ll + 3][c]) * wv.w;
    float v = sacc / (1.f + expf(-sacc));
    int gl = l0 + ll;
    if (isC) {
      cb[(size_t)gl * DS + (gc - (DI + DS))] = f2bf(v);
    } else if (isX) {
      xs[(size_t)gl * DI + gc] = f2bf(v);
      ot[c][ll] = f2bf(v * sl[ll]);
    } else {
      ot[c][ll] = f2bf(v);
    }
  }
  if (!isC) {
    __syncthreads();
#pragma unroll
    for (int j = 0; j < 4; ++j) {
      int linear = j * 1024 + t * 4;
      int rr = linear >> 6;
      int lc = linear & 63;
      *(u16x4*)&OpT[(size_t)(c0 + rr) * L_SEQ + l0 + lc] = *(const u16x4*)&ot[rr][lc];
    }
  }
}

// ---------------------------------------------------------------------------
// Ht[p][n] = bf16( sum_z Ppart[z][n][p] )
// ---------------------------------------------------------------------------
__global__ __launch_bounds__(256)
void h_reduce_t_kernel(const float* __restrict__ P, unsigned short* __restrict__ Ht) {
  __shared__ float tile[32][65];
  const int bid = blockIdx.x;
  const int pt = bid & 31, ng = bid >> 5;
  const int t = threadIdx.x;
#pragma unroll
  for (int i = 0; i < 8; ++i) {
    int nl = i * 4 + (t >> 6);
    int n = ng * 32 + nl;
    int p = pt * 64 + (t & 63);
    float acc = 0.f;
#pragma unroll
    for (int z = 0; z < KSPLIT; ++z)
      acc += P[(size_t)z * (DS * DI) + (size_t)n * DI + p];
    tile[nl][t & 63] = acc;
  }
  __syncthreads();
#pragma unroll
  for (int j = 0; j < 8; ++j) {
    int linear = j * 256 + t;
    int pl = linear >> 5, nl = linear & 31;
    Ht[(size_t)(pt * 64 + pl) * DS + ng * 32 + nl] = f2bf(tile[nl][pl]);
  }
}

// ---------------------------------------------------------------------------
// LayerNorm over 2048 (bf16 y) + z-gate (bf16 z); bf16 yz into zxb [2048,4096)
// ---------------------------------------------------------------------------
__global__ __launch_bounds__(256)
void ln_mul_kernel(const unsigned short* __restrict__ ybuf, unsigned short* __restrict__ zxb,
                   const float* __restrict__ ln_w, const float* __restrict__ ln_b) {
  int l = blockIdx.x;
  int t = threadIdx.x;
  int c0 = t * 8;
  u16x8 yv = *(const u16x8*)&ybuf[(size_t)l * DI + c0];
  float vals[8];
  float s = 0.f, sq = 0.f;
#pragma unroll
  for (int i = 0; i < 8; ++i) {
    float v = bf2f(yv[i]);
    vals[i] = v;
    s += v;
    sq += v * v;
  }
#pragma unroll
  for (int off = 32; off > 0; off >>= 1) {
    s += __shfl_down(s, off, 64);
    sq += __shfl_down(sq, off, 64);
  }
  __shared__ float red[10];
  int wave = t >> 6, lane = t & 63;
  if (lane == 0) { red[wave] = s; red[4 + wave] = sq; }
  __syncthreads();
  if (t == 0) {
    float S = red[0] + red[1] + red[2] + red[3];
    float SQ = red[4] + red[5] + red[6] + red[7];
    float mu = S / (float)DI;
    red[8] = mu;
    red[9] = rsqrtf(SQ / (float)DI - mu * mu + 1e-5f);
  }
  __syncthreads();
  float mu = red[8], rstd = red[9];
  unsigned short* zrow = zxb + (size_t)l * DPROJ;
  u16x8 zv = *(const u16x8*)&zrow[c0];
  float4 w0 = *(const float4*)&ln_w[c0], w1 = *(const float4*)&ln_w[c0 + 4];
  float4 b0 = *(const float4*)&ln_b[c0], b1 = *(const float4*)&ln_b[c0 + 4];
  float w[8] = {w0.x, w0.y, w0.z, w0.w, w1.x, w1.y, w1.z, w1.w};
  float b[8] = {b0.x, b0.y, b0.z, b0.w, b1.x, b1.y, b1.z, b1.w};
  u16x8 o;
#pragma unroll
  for (int i = 0; i < 8; ++i) {
    float v = (vals[i] - mu) * rstd * w[i] + b[i];
    o[i] = f2bf(v * bf2f(zv[i]));
  }
  *(u16x8*)&zrow[DI + c0] = o;
}

// ---------------------------------------------------------------------------
extern "C" void kernel_launch(void* const* d_in, const int* in_sizes, int n_in,
                              void* d_out, int out_size, void* d_ws, size_t ws_size,
                              hipStream_t stream) {
  const float* x       = (const float*)d_in[0];
  const float* W_in    = (const float*)d_in[1];
  const float* W_conv  = (const float*)d_in[2];
  const float* b_conv  = (const float*)d_in[3];
  const float* dt_bias = (const float*)d_in[4];
  const float* A_log   = (const float*)d_in[5];
  const float* D_param = (const float*)d_in[6];
  const float* ln_w    = (const float*)d_in[7];
  const float* ln_b    = (const float*)d_in[8];
  const float* W_out   = (const float*)d_in[9];
  float* out = (float*)d_out;

  // ---- workspace layout ----
  unsigned short* zxb = (unsigned short*)d_ws;           // L*4384 bf16
  unsigned short* xs   = zxb + (size_t)L_SEQ * DPROJ;    // L*2048 bf16
  unsigned short* cb   = xs + (size_t)L_SEQ * DI;        // L*128 bf16
  float* svec = (float*)(cb + (size_t)L_SEQ * DS);       // L*32 f32
  unsigned short* OpT = (unsigned short*)(svec + (size_t)L_SEQ * NH);  // 2176*8192 bf16
  float* Ppart = (float*)(OpT + (size_t)OPROWS * L_SEQ); // KSPLIT*128*2048 f32
  unsigned short* Ht = (unsigned short*)(Ppart + (size_t)KSPLIT * DS * DI);  // 2048*128
  unsigned short* wout_bf16 = Ht + (size_t)DI * DS;      // 1024*2048 bf16
  // aliases in OpT's dead windows:
  unsigned short* x_bf16   = OpT;                        // casts..GEMM1 (16 MB)
  unsigned short* win_bf16 = OpT + (size_t)L_SEQ * DM;   // casts..GEMM1 (9.4 MB)
  unsigned short* ybuf     = OpT;                        // Y-GEMM..ln_mul (33.5 MB)

  // 0) all casts in one dispatch
  cast_all_kernel<<<14848, 256, 0, stream>>>(x, W_in, W_out, x_bf16, win_bf16,
                                             wout_bf16);

  // 1) zxb = bf16( x @ W_in^T )  (M=8192, N=4608 pad, K=1024)
  //    128x128 TLP3+swz, 48 KB LDS -> 3 blocks/CU; grid 36x64 = 2304
  gemm128_tlp3<0><<<dim3(NPAD_IN / 128, L_SEQ / 128), 512, 0, stream>>>(
      x_bf16, DM, win_bf16, DM, zxb, DPROJ, DM, DPROJ);

  // 2) s = a*dt
  dt_kernel<<<(L_SEQ * NH) / 256, 256, 0, stream>>>(zxb, dt_bias, A_log, svec);

  // 3) conv + silu + transpose-pack (clobbers x_bf16/win_bf16 — dead)
  conv_fused_kernel<<<dim3(CDIM / 64, L_SEQ / 64), 256, 0, stream>>>(
      zxb, W_conv, b_conv, svec, xs, cb, OpT);

  // 4) Hcat = B^T @ Vs : M=128, N=2048, K=8192, split-K=16 (256 blocks, f32 out)
  gemm_bt_mfma<2><<<dim3(DI / 128, 1, KSPLIT), 256, 0, stream>>>(
      OpT + (size_t)DI * L_SEQ, L_SEQ, OpT, L_SEQ, Ppart, DI, L_SEQ, DI,
      nullptr, nullptr);

  // 5) reduce partials + transpose -> Ht (2048 x 128 bf16)
  h_reduce_t_kernel<<<128, 256, 0, stream>>>(Ppart, Ht);

  // 6) y = C @ Hcat + D*x_ssm : M=8192, N=2048, K=128, bf16 repacked out
  gemm_bt_mfma<1><<<dim3(DI / 128, L_SEQ / 128), 256, 0, stream>>>(
      cb, DS, Ht, DS, ybuf, DI, DS, DI, xs, D_param);

  // 7) LN + z-gate -> bf16 yz into zxb cols [2048,4096)
  ln_mul_kernel<<<L_SEQ, 256, 0, stream>>>(ybuf, zxb, ln_w, ln_b);

  // 8) out = yz @ W_out^T : M=8192, N=1024, K=2048
  //    128x128 TLP3+swz f32 out: grid 8 x 64 = 512 blocks
  gemm128_tlp3<1><<<dim3(DM / 128, L_SEQ / 128), 512, 0, stream>>>(
      zxb + DI, DPROJ, wout_bf16, DI, out, DM, DI, DM);
}

// Round 8
// 328.883 us; speedup vs baseline: 1.0464x; 1.0342x over previous
//
#include <hip/hip_runtime.h>
#include <hip/hip_bf16.h>
#include <math.h>

#define L_SEQ 8192
#define DM 1024
#define DI 2048
#define NH 32
#define HD 64
#define DS 128
#define CDIM 2304
#define DPROJ 4384
#define NPAD_IN 4608  // 36*128 / 18*256, zero-padded W_in rows
#define KSPLIT 16
#define OPROWS 2176   // 2048 Vs^T rows + 128 B^T rows

typedef short bf16x8 __attribute__((ext_vector_type(8)));
typedef float floatx4 __attribute__((ext_vector_type(4)));
typedef unsigned short u16x4 __attribute__((ext_vector_type(4)));
typedef unsigned short u16x8 __attribute__((ext_vector_type(8)));

#define AS1(p) ((const __attribute__((address_space(1))) void*)(p))
#define AS3(p) ((__attribute__((address_space(3))) void*)(p))

__device__ __forceinline__ float bf2f(unsigned short u) {
  union { unsigned int i; float f; } c; c.i = ((unsigned int)u) << 16; return c.f;
}
__device__ __forceinline__ unsigned short f2bf(float f) {
  return __bfloat16_as_ushort(__float2bfloat16(f));
}

// ---------------------------------------------------------------------------
// v4: 256x128-tile bf16 GEMM, per-wave 64x64 regs -> 1.5x less LDS read traffic.
// r7 post-mortem: structure was LDS-READ-bound (~770 cyc/kt reads vs 620 MFMA;
// r5=87us and r7=97us both sit on that roofline; occupancy couldn't help).
// Amplification math: 128x128 tile, 2Mx4N waves: reads = 4xA + 2xB = 48KB/kt
// per 524k MAC (0.0916 B/MAC). THIS kernel: 256x128 tile, 4Mx2N waves,
// per-wave 64x64 (acc[4][4]=64 VGPR): reads = 2xA(16KB) + 4xB(8KB) = 64KB/kt
// per 1049k MAC (0.061 B/MAC) -> LDS roofline ~58us for GEMM1 (was ~86).
// C[m,n] = sum_k A[m,k]*B[n,k]. 512 thr = 8 waves (wm=w&3 over M, wn=w>>2
// over N). BK=32, NT=K/32. LDS 72KB = 3 ring slots x (A 16KB + B 8KB)
// -> 2 blocks/CU (144KB of 160). __launch_bounds__(512,4): VGPR cap 128,
// need ~105 (acc64 + af16 + bb8 + addr). WRITE_SIZE is the spill canary.
// Layout (r7-proven paired-row + XOR involution, rule #21 both-sides):
//   A region 16KB = 128 LDS rows x 128B; LDS row r holds m-rows r (bytes
//   [0,64)) and r+128 (bytes [64,128)). B region 8KB = 64 rows x 128B,
//   row r holds n-rows r and r+64. Involution byte ^= ((byte>>7)&7)<<4.
//   Staging: LINEAR dest + deswizzled global source (bijective).
//   Frag read: chunk = ((half<<2)|quad) ^ (fr&7) -> 16 lanes over 8 slots,
//   2-way aliasing = free (m136). Deswizzle check: read returns m-row R,
//   K bytes quad*16..+16 = mfma K elems quad*8..+8. [hand-verified]
// Schedule per kt (slot cur=kt%3), ONE barrier per kt:
//   4 rdA + 2 rdB; stage kt+2 -> slot (cur+2)%3 (3 gload; slot holds kt-1,
//   reads done 1 barrier back); lgkm(0); prio1; 8 MFMA (n-half 0); prio0;
//   2 rdB (n-half 1, reuse bb); lgkm(0); prio1; 8 MFMA; prio0;
//   vmcnt(3) [drains kt+1] | vmcnt(0) at tail; barrier.
// vmcnt ledger (3 gload per stage): prologue kt0(3)+kt1(3), vmcnt(3)=kt0.
//   Steady: outstanding kt+1(3)+kt+2(3); vmcnt(3) drains kt+1. Tail kt=NT-2:
//   no stage, vmcnt(0). kt=NT-1: no trailing wait.
// OMODE 0: bf16 out via LDS repack (64KB <= 72KB) after __syncthreads,
//   full-line u16x8 stores, Nstore guard (8-col runs). OMODE 1: f32 direct.
// ---------------------------------------------------------------------------
template <int OMODE>
__global__ __launch_bounds__(512, 4)
void gemm_v4(const unsigned short* __restrict__ A, int lda,
             const unsigned short* __restrict__ B, int ldb,
             void* __restrict__ Cout, int ldc,
             int K, int Nstore) {
  __shared__ __align__(16) char lds[73728];
  const int t = threadIdx.x;
  const int lane = t & 63;
  const int w = t >> 6;
  const int wm = w & 3, wn = w >> 2;
  const int fr = lane & 15, quad = lane >> 4;

  // bijective XCD swizzle: xcd owns a contiguous m-band, m-fastest within n
  int gx = gridDim.x, gy = gridDim.y;
  int linear = blockIdx.y * gx + blockIdx.x;
  int xcd = linear & 7, loc = linear >> 3;
  int mper = gy >> 3;                       // gy must be %8==0 (32 here)
  int mt = xcd * mper + loc % mper;
  int nt = loc / mper;
  const int m0 = mt << 8, n0 = nt << 7;
  const int NT = K >> 5;

  floatx4 acc[4][4];
#pragma unroll
  for (int i = 0; i < 4; ++i)
#pragma unroll
    for (int j = 0; j < 4; ++j) acc[i][j] = (floatx4){0.f, 0.f, 0.f, 0.f};
  bf16x8 af[4], bb[2];

  // ---- staging: linear LDS dest; source = deswizzled (R, kb) for dest o
  auto stA = [&](int slot, int kt) {
#pragma unroll
    for (int i = 0; i < 2; ++i) {
      int o = i * 8192 + t * 16;                 // [0,16384)
      int os = o ^ (((o >> 7) & 7) << 4);
      int r128 = os >> 7;                        // [0,128)
      int half = (os >> 6) & 1;
      int kb = os & 63;
      int R = (half << 7) | r128;                // m-row [0,256)
      const unsigned short* src = A + (size_t)(m0 + R) * lda + (kt << 5) + (kb >> 1);
      __builtin_amdgcn_global_load_lds(AS1(src), AS3(lds + slot * 24576 + o), 16, 0, 0);
    }
  };
  auto stB = [&](int slot, int kt) {
    int o = t * 16;                              // [0,8192)
    int os = o ^ (((o >> 7) & 7) << 4);
    int r64 = os >> 7;                           // [0,64)
    int half = (os >> 6) & 1;
    int kb = os & 63;
    int R = (half << 6) | r64;                   // n-row [0,128)
    const unsigned short* src = B + (size_t)(n0 + R) * ldb + (kt << 5) + (kb >> 1);
    __builtin_amdgcn_global_load_lds(AS1(src), AS3(lds + slot * 24576 + 16384 + o), 16, 0, 0);
  };
  // ---- swizzled fragment reads
  auto rdA = [&](int slot, int mi) -> bf16x8 {
    int R = (wm << 6) | (mi << 4) | fr;          // [0,256)
    int r128 = R & 127, half = R >> 7;
    int chunk = ((half << 2) | quad) ^ (fr & 7);
    return *(const bf16x8*)(lds + slot * 24576 + r128 * 128 + chunk * 16);
  };
  auto rdB = [&](int slot, int ni) -> bf16x8 {
    int R = (wn << 6) | (ni << 4) | fr;          // [0,128)
    int r64 = R & 63, half = R >> 6;
    int chunk = ((half << 2) | quad) ^ (fr & 7);
    return *(const bf16x8*)(lds + slot * 24576 + 16384 + r64 * 128 + chunk * 16);
  };

  // ---- prologue: stage kt0 + kt1; vmcnt(3) -> kt0 landed
  stA(0, 0); stB(0, 0);
  if (NT > 1) {
    stA(1, 1); stB(1, 1);
    asm volatile("s_waitcnt vmcnt(3)" ::: "memory");
  } else {
    asm volatile("s_waitcnt vmcnt(0)" ::: "memory");
  }
  __builtin_amdgcn_s_barrier();

  int cur = 0;
  for (int kt = 0; kt < NT; ++kt) {
    const bool pf = (kt + 2 < NT);
    // reads from slot cur (n-half 0)
#pragma unroll
    for (int mi = 0; mi < 4; ++mi) af[mi] = rdA(cur, mi);
    bb[0] = rdB(cur, 0); bb[1] = rdB(cur, 1);
    // stage kt+2 into slot (cur+2)%3 (holds kt-1; reads done 1 barrier back)
    if (pf) {
      int s2 = cur + 2; if (s2 >= 3) s2 -= 3;
      stA(s2, kt + 2); stB(s2, kt + 2);
    }
    asm volatile("s_waitcnt lgkmcnt(0)" ::: "memory");
    __builtin_amdgcn_s_setprio(1);
#pragma unroll
    for (int mi = 0; mi < 4; ++mi) {
      acc[mi][0] = __builtin_amdgcn_mfma_f32_16x16x32_bf16(af[mi], bb[0], acc[mi][0], 0, 0, 0);
      acc[mi][1] = __builtin_amdgcn_mfma_f32_16x16x32_bf16(af[mi], bb[1], acc[mi][1], 0, 0, 0);
    }
    __builtin_amdgcn_s_setprio(0);
    // n-half 1 (reuse bb registers)
    bb[0] = rdB(cur, 2); bb[1] = rdB(cur, 3);
    asm volatile("s_waitcnt lgkmcnt(0)" ::: "memory");
    __builtin_amdgcn_s_setprio(1);
#pragma unroll
    for (int mi = 0; mi < 4; ++mi) {
      acc[mi][2] = __builtin_amdgcn_mfma_f32_16x16x32_bf16(af[mi], bb[0], acc[mi][2], 0, 0, 0);
      acc[mi][3] = __builtin_amdgcn_mfma_f32_16x16x32_bf16(af[mi], bb[1], acc[mi][3], 0, 0, 0);
    }
    __builtin_amdgcn_s_setprio(0);
    if (kt < NT - 1) {
      if (pf) asm volatile("s_waitcnt vmcnt(3)" ::: "memory");  // kt+1 landed
      else    asm volatile("s_waitcnt vmcnt(0)" ::: "memory");
      __builtin_amdgcn_s_barrier();
    }
    ++cur; if (cur == 3) cur = 0;
  }

  if (OMODE == 0) {
    // ---- epilogue: repack 256x128 bf16 through LDS (64KB), full-line stores
    __syncthreads();                   // all LDS reads done before reuse
    unsigned short* rp = (unsigned short*)lds;
    unsigned short* C = (unsigned short*)Cout;
    const int mb = wm * 64, nb = wn * 64;
#pragma unroll
    for (int mi = 0; mi < 4; ++mi)
#pragma unroll
      for (int ni = 0; ni < 4; ++ni)
#pragma unroll
        for (int r = 0; r < 4; ++r)
          rp[(mb + mi * 16 + quad * 4 + r) * 128 + nb + ni * 16 + fr] = f2bf(acc[mi][ni][r]);
    __syncthreads();
#pragma unroll
    for (int j = 0; j < 8; ++j) {
      int lin = j * 4096 + t * 8;
      int row = lin >> 7, col = lin & 127;
      int gcol = n0 + col;
      if (gcol < Nstore)
        *(u16x8*)&C[(size_t)(m0 + row) * ldc + gcol] = *(const u16x8*)&rp[lin];
    }
  } else {
    // ---- f32 direct frag stores: 16 consecutive lanes -> 64B segments
    float* Cf = (float*)Cout;
#pragma unroll
    for (int mi = 0; mi < 4; ++mi)
#pragma unroll
      for (int ni = 0; ni < 4; ++ni) {
        int gcol = n0 + wn * 64 + ni * 16 + fr;
        int grow = m0 + wm * 64 + mi * 16 + quad * 4;
#pragma unroll
        for (int r = 0; r < 4; ++r)
          if (gcol < Nstore)
            Cf[(size_t)(grow + r) * ldc + gcol] = acc[mi][ni][r];
      }
  }
}

// ---------------------------------------------------------------------------
// bf16 MFMA GEMM: C[m,n] = sum_k A[m,k]*B[n,k]  (K contiguous both operands)
// 128x128 tile, BK=32, 4 waves (2x2), 4x4 frags of 16x16x32 each.
// (Retained for MODE 1 (fused D-add, K=128) and MODE 2 (split-K).)
// ---------------------------------------------------------------------------
template <int MODE>
__global__ __launch_bounds__(256)
void gemm_bt_mfma(const unsigned short* __restrict__ A, int lda,
                  const unsigned short* __restrict__ B, int ldb,
                  void* __restrict__ Cout, int ldc,
                  int Kfull, int Nstore,
                  const unsigned short* __restrict__ xs,
                  const float* __restrict__ Dvec) {
  __shared__ __align__(16) char smem[17408];  // staging 16 KB; f32 repack 17 KB
  unsigned short* Asm = (unsigned short*)smem;
  unsigned short* Bsm = Asm + 128 * 32;
  const int t = threadIdx.x;

  int bx = blockIdx.x, by = blockIdx.y;
  if (MODE != 2) {
    int gx = gridDim.x;
    int linear = by * gx + bx;
    int xcd = linear & 7;
    int local = linear >> 3;
    by = xcd * 8 + (local & 7);
    bx = local >> 3;
  }
  const int m0 = by * 128;
  const int n0 = bx * 128;

  int kstart = 0, klen = Kfull;
  if (MODE == 2) { klen = Kfull / KSPLIT; kstart = blockIdx.z * klen; }
  const int wave = t >> 6, lane = t & 63;
  const int wm = (wave & 1) * 64;
  const int wn = (wave >> 1) * 64;
  const int fr = lane & 15;
  const int quad = lane >> 4;

  floatx4 acc[4][4];
#pragma unroll
  for (int i = 0; i < 4; ++i)
#pragma unroll
    for (int j = 0; j < 4; ++j) acc[i][j] = (floatx4){0.f, 0.f, 0.f, 0.f};

  for (int k0 = kstart; k0 < kstart + klen; k0 += 32) {
#pragma unroll
    for (int i = 0; i < 2; ++i) {
      int linear = i * 256 + t;          // 0..511
      int row = linear >> 2;             // 0..127
      int kq = (linear & 3) * 8;         // bf16 elem offset in K
      const unsigned short* ga = A + (size_t)(m0 + row) * lda + (k0 + kq);
      const unsigned short* gb = B + (size_t)(n0 + row) * ldb + (k0 + kq);
      __builtin_amdgcn_global_load_lds(AS1(ga), AS3(&Asm[linear * 8]), 16, 0, 0);
      __builtin_amdgcn_global_load_lds(AS1(gb), AS3(&Bsm[linear * 8]), 16, 0, 0);
    }
    __syncthreads();

    bf16x8 af[4], bfr[4];
#pragma unroll
    for (int i = 0; i < 4; ++i) {
      af[i]  = *(const bf16x8*)&Asm[(wm + i * 16 + fr) * 32 + quad * 8];
      bfr[i] = *(const bf16x8*)&Bsm[(wn + i * 16 + fr) * 32 + quad * 8];
    }
#pragma unroll
    for (int mi = 0; mi < 4; ++mi)
#pragma unroll
      for (int ni = 0; ni < 4; ++ni)
        acc[mi][ni] = __builtin_amdgcn_mfma_f32_16x16x32_bf16(
            af[mi], bfr[ni], acc[mi][ni], 0, 0, 0);
    __syncthreads();
  }

  // C/D frag layout: col = lane&15, row = (lane>>4)*4 + r  [m89-verified]
  const int lrbase = (wm ? 16 : 0) + quad * 4;
  if (MODE == 0 || MODE == 1) {
    unsigned short(*rp)[136] = (unsigned short(*)[136])smem;
    unsigned short* C = (unsigned short*)Cout;
#pragma unroll
    for (int mi = 0; mi < 4; ++mi) {
      __syncthreads();
#pragma unroll
      for (int ni = 0; ni < 4; ++ni)
#pragma unroll
        for (int r = 0; r < 4; ++r)
          rp[lrbase + r][wn + ni * 16 + fr] = f2bf(acc[mi][ni][r]);
      __syncthreads();
#pragma unroll
      for (int j = 0; j < 2; ++j) {
        int off = j * 2048 + t * 8;          // elem in 32x128 group
        int lr = off >> 7, c = off & 127;
        int grow = m0 + (lr >> 4) * 64 + mi * 16 + (lr & 15);
        int gcol = n0 + c;
        u16x8 v = *(const u16x8*)&rp[lr][c];
        if (MODE == 1) {
          u16x8 xv = *(const u16x8*)&xs[(size_t)grow * ldc + gcol];
          float Dh = Dvec[gcol >> 6];
          u16x8 o;
#pragma unroll
          for (int e = 0; e < 8; ++e) o[e] = f2bf(bf2f(v[e]) + Dh * bf2f(xv[e]));
          *(u16x8*)&C[(size_t)grow * ldc + gcol] = o;
        } else {
          if (gcol < Nstore) *(u16x8*)&C[(size_t)grow * ldc + gcol] = v;
        }
      }
    }
  } else {
    float(*rpf)[136] = (float(*)[136])smem;  // 32*136*4 = 17408 B
    float* C = (float*)Cout;
    if (MODE == 2) C += (size_t)blockIdx.z * DS * DI;
#pragma unroll
    for (int mi = 0; mi < 4; ++mi) {
      __syncthreads();
#pragma unroll
      for (int ni = 0; ni < 4; ++ni)
#pragma unroll
        for (int r = 0; r < 4; ++r)
          rpf[lrbase + r][wn + ni * 16 + fr] = acc[mi][ni][r];
      __syncthreads();
#pragma unroll
      for (int j = 0; j < 4; ++j) {
        int off = j * 1024 + t * 4;          // elem in 32x128 group
        int lr = off >> 7, c = off & 127;
        int grow = m0 + (lr >> 4) * 64 + mi * 16 + (lr & 15);
        int gcol = n0 + c;
        float4 v = *(const float4*)&rpf[lr][c];
        *(float4*)&C[(size_t)grow * ldc + gcol] = v;
      }
    }
  }
}

// ---------------------------------------------------------------------------
// One merged cast dispatch. Regions (in 256-thread blocks of 4-elem quads):
//   [0, 8192):        x       (8192x1024 f32 -> bf16)
//   [8192, 12800):    W_in    (4384x1024 -> 4608x1024 bf16, pad rows zero)
//   [12800, 14848):   W_out   (1024x2048 f32 -> bf16)
// ---------------------------------------------------------------------------
__global__ __launch_bounds__(256)
void cast_all_kernel(const float* __restrict__ x, const float* __restrict__ W_in,
                     const float* __restrict__ W_out,
                     unsigned short* __restrict__ x_bf16,
                     unsigned short* __restrict__ win_bf16,
                     unsigned short* __restrict__ wout_bf16) {
  int b = blockIdx.x;
  int t = threadIdx.x;
  u16x4 o = (u16x4){0, 0, 0, 0};
  if (b < 8192) {
    size_t i4 = ((size_t)b * 256 + t) * 4;
    float4 v = *(const float4*)(x + i4);
    o.x = f2bf(v.x); o.y = f2bf(v.y); o.z = f2bf(v.z); o.w = f2bf(v.w);
    *(u16x4*)(x_bf16 + i4) = o;
  } else if (b < 12800) {
    size_t i4 = ((size_t)(b - 8192) * 256 + t) * 4;  // over 4608*1024
    int row = (int)(i4 >> 10);
    if (row < DPROJ) {
      float4 v = *(const float4*)(W_in + i4);
      o.x = f2bf(v.x); o.y = f2bf(v.y); o.z = f2bf(v.z); o.w = f2bf(v.w);
    }
    *(u16x4*)(win_bf16 + i4) = o;
  } else {
    size_t i4 = ((size_t)(b - 12800) * 256 + t) * 4;
    float4 v = *(const float4*)(W_out + i4);
    o.x = f2bf(v.x); o.y = f2bf(v.y); o.z = f2bf(v.z); o.w = f2bf(v.w);
    *(u16x4*)(wout_bf16 + i4) = o;
  }
}

// ---------------------------------------------------------------------------
// s[l,h] = dt * exp(-dt*exp(A_log[h])),  dt = softplus(zxb[l,4352+h]+dt_bias[h])
// ---------------------------------------------------------------------------
__global__ __launch_bounds__(256)
void dt_kernel(const unsigned short* __restrict__ zxb, const float* __restrict__ dt_bias,
               const float* __restrict__ A_log, float* __restrict__ s_out) {
  int idx = blockIdx.x * 256 + threadIdx.x;  // l*32 + h
  int l = idx >> 5, h = idx & 31;
  float v = bf2f(zxb[(size_t)l * DPROJ + (DI + CDIM) + h]) + dt_bias[h];
  float d = (v > 20.f) ? v : log1pf(expf(v));
  s_out[idx] = d * expf(-d * expf(A_log[h]));
}

// ---------------------------------------------------------------------------
// Fused conv+silu+transpose. Block = 64 channels x 64 l, 256 threads.
// ---------------------------------------------------------------------------
__global__ __launch_bounds__(256)
void conv_fused_kernel(const unsigned short* __restrict__ zxb,
                       const float* __restrict__ Wc,
                       const float* __restrict__ bc,
                       const float* __restrict__ svec,
                       unsigned short* __restrict__ xs,
                       unsigned short* __restrict__ cb,
                       unsigned short* __restrict__ OpT) {
  __shared__ unsigned short zt[67][66];
  __shared__ unsigned short ot[64][66];
  __shared__ float sl[64];
  const int c0 = blockIdx.x * 64;
  const int l0 = blockIdx.y * 64;
  const int t = threadIdx.x;
  for (int idx = t; idx < 67 * 16; idx += 256) {
    int row = idx >> 4;
    int colq = (idx & 15) * 4;
    int gl = l0 - 1 + row;
    u16x4 v = (u16x4){0, 0, 0, 0};
    if (gl >= 0 && gl < L_SEQ)
      v = *(const u16x4*)&zxb[(size_t)gl * DPROJ + DI + c0 + colq];
    *(u16x4*)&zt[row][colq] = v;
  }
  const bool isX = (c0 < DI);
  const bool isC = (c0 >= DI + DS);
  if (isX && t < 64) sl[t] = svec[(size_t)(l0 + t) * NH + (c0 >> 6)];
  const int c = t & 63;
  const int gc = c0 + c;
  const float4 wv = *(const float4*)&Wc[gc * 4];
  const float bias = bc[gc];
  const int lq = (t >> 6) * 16;
  __syncthreads();
#pragma unroll
  for (int i = 0; i < 16; ++i) {
    int ll = lq + i;
    float sacc = bias + bf2f(zt[ll][c]) * wv.x + bf2f(zt[ll + 1][c]) * wv.y +
                 bf2f(zt[ll + 2][c]) * wv.z + bf2f(zt[ll + 3][c]) * wv.w;
    float v = sacc / (1.f + expf(-sacc));
    int gl = l0 + ll;
    if (isC) {
      cb[(size_t)gl * DS + (gc - (DI + DS))] = f2bf(v);
    } else if (isX) {
      xs[(size_t)gl * DI + gc] = f2bf(v);
      ot[c][ll] = f2bf(v * sl[ll]);
    } else {
      ot[c][ll] = f2bf(v);
    }
  }
  if (!isC) {
    __syncthreads();
#pragma unroll
    for (int j = 0; j < 4; ++j) {
      int linear = j * 1024 + t * 4;
      int rr = linear >> 6;
      int lc = linear & 63;
      *(u16x4*)&OpT[(size_t)(c0 + rr) * L_SEQ + l0 + lc] = *(const u16x4*)&ot[rr][lc];
    }
  }
}

// ---------------------------------------------------------------------------
// Ht[p][n] = bf16( sum_z Ppart[z][n][p] )
// ---------------------------------------------------------------------------
__global__ __launch_bounds__(256)
void h_reduce_t_kernel(const float* __restrict__ P, unsigned short* __restrict__ Ht) {
  __shared__ float tile[32][65];
  const int bid = blockIdx.x;
  const int pt = bid & 31, ng = bid >> 5;
  const int t = threadIdx.x;
#pragma unroll
  for (int i = 0; i < 8; ++i) {
    int nl = i * 4 + (t >> 6);
    int n = ng * 32 + nl;
    int p = pt * 64 + (t & 63);
    float acc = 0.f;
#pragma unroll
    for (int z = 0; z < KSPLIT; ++z)
      acc += P[(size_t)z * (DS * DI) + (size_t)n * DI + p];
    tile[nl][t & 63] = acc;
  }
  __syncthreads();
#pragma unroll
  for (int j = 0; j < 8; ++j) {
    int linear = j * 256 + t;
    int pl = linear >> 5, nl = linear & 31;
    Ht[(size_t)(pt * 64 + pl) * DS + ng * 32 + nl] = f2bf(tile[nl][pl]);
  }
}

// ---------------------------------------------------------------------------
// LayerNorm over 2048 (bf16 y) + z-gate (bf16 z); bf16 yz into zxb [2048,4096)
// ---------------------------------------------------------------------------
__global__ __launch_bounds__(256)
void ln_mul_kernel(const unsigned short* __restrict__ ybuf, unsigned short* __restrict__ zxb,
                   const float* __restrict__ ln_w, const float* __restrict__ ln_b) {
  int l = blockIdx.x;
  int t = threadIdx.x;
  int c0 = t * 8;
  u16x8 yv = *(const u16x8*)&ybuf[(size_t)l * DI + c0];
  float vals[8];
  float s = 0.f, sq = 0.f;
#pragma unroll
  for (int i = 0; i < 8; ++i) {
    float v = bf2f(yv[i]);
    vals[i] = v;
    s += v;
    sq += v * v;
  }
#pragma unroll
  for (int off = 32; off > 0; off >>= 1) {
    s += __shfl_down(s, off, 64);
    sq += __shfl_down(sq, off, 64);
  }
  __shared__ float red[10];
  int wave = t >> 6, lane = t & 63;
  if (lane == 0) { red[wave] = s; red[4 + wave] = sq; }
  __syncthreads();
  if (t == 0) {
    float S = red[0] + red[1] + red[2] + red[3];
    float SQ = red[4] + red[5] + red[6] + red[7];
    float mu = S / (float)DI;
    red[8] = mu;
    red[9] = rsqrtf(SQ / (float)DI - mu * mu + 1e-5f);
  }
  __syncthreads();
  float mu = red[8], rstd = red[9];
  unsigned short* zrow = zxb + (size_t)l * DPROJ;
  u16x8 zv = *(const u16x8*)&zrow[c0];
  float4 w0 = *(const float4*)&ln_w[c0], w1 = *(const float4*)&ln_w[c0 + 4];
  float4 b0 = *(const float4*)&ln_b[c0], b1 = *(const float4*)&ln_b[c0 + 4];
  float w[8] = {w0.x, w0.y, w0.z, w0.w, w1.x, w1.y, w1.z, w1.w};
  float b[8] = {b0.x, b0.y, b0.z, b0.w, b1.x, b1.y, b1.z, b1.w};
  u16x8 o;
#pragma unroll
  for (int i = 0; i < 8; ++i) {
    float v = (vals[i] - mu) * rstd * w[i] + b[i];
    o[i] = f2bf(v * bf2f(zv[i]));
  }
  *(u16x8*)&zrow[DI + c0] = o;
}

// ---------------------------------------------------------------------------
extern "C" void kernel_launch(void* const* d_in, const int* in_sizes, int n_in,
                              void* d_out, int out_size, void* d_ws, size_t ws_size,
                              hipStream_t stream) {
  const float* x       = (const float*)d_in[0];
  const float* W_in    = (const float*)d_in[1];
  const float* W_conv  = (const float*)d_in[2];
  const float* b_conv  = (const float*)d_in[3];
  const float* dt_bias = (const float*)d_in[4];
  const float* A_log   = (const float*)d_in[5];
  const float* D_param = (const float*)d_in[6];
  const float* ln_w    = (const float*)d_in[7];
  const float* ln_b    = (const float*)d_in[8];
  const float* W_out   = (const float*)d_in[9];
  float* out = (float*)d_out;

  // ---- workspace layout ----
  unsigned short* zxb = (unsigned short*)d_ws;           // L*4384 bf16
  unsigned short* xs   = zxb + (size_t)L_SEQ * DPROJ;    // L*2048 bf16
  unsigned short* cb   = xs + (size_t)L_SEQ * DI;        // L*128 bf16
  float* svec = (float*)(cb + (size_t)L_SEQ * DS);       // L*32 f32
  unsigned short* OpT = (unsigned short*)(svec + (size_t)L_SEQ * NH);  // 2176*8192 bf16
  float* Ppart = (float*)(OpT + (size_t)OPROWS * L_SEQ); // KSPLIT*128*2048 f32
  unsigned short* Ht = (unsigned short*)(Ppart + (size_t)KSPLIT * DS * DI);  // 2048*128
  unsigned short* wout_bf16 = Ht + (size_t)DI * DS;      // 1024*2048 bf16
  // aliases in OpT's dead windows:
  unsigned short* x_bf16   = OpT;                        // casts..GEMM1 (16 MB)
  unsigned short* win_bf16 = OpT + (size_t)L_SEQ * DM;   // casts..GEMM1 (9.4 MB)
  unsigned short* ybuf     = OpT;                        // Y-GEMM..ln_mul (33.5 MB)

  // 0) all casts in one dispatch
  cast_all_kernel<<<14848, 256, 0, stream>>>(x, W_in, W_out, x_bf16, win_bf16,
                                             wout_bf16);

  // 1) zxb = bf16( x @ W_in^T )  (M=8192, N=4608 pad, K=1024)
  //    256x128 v4, 72 KB LDS -> 2 blocks/CU; grid 36 x 32 = 1152 blocks
  gemm_v4<0><<<dim3(NPAD_IN / 128, L_SEQ / 256), 512, 0, stream>>>(
      x_bf16, DM, win_bf16, DM, zxb, DPROJ, DM, DPROJ);

  // 2) s = a*dt
  dt_kernel<<<(L_SEQ * NH) / 256, 256, 0, stream>>>(zxb, dt_bias, A_log, svec);

  // 3) conv + silu + transpose-pack (clobbers x_bf16/win_bf16 — dead)
  conv_fused_kernel<<<dim3(CDIM / 64, L_SEQ / 64), 256, 0, stream>>>(
      zxb, W_conv, b_conv, svec, xs, cb, OpT);

  // 4) Hcat = B^T @ Vs : M=128, N=2048, K=8192, split-K=16 (256 blocks, f32 out)
  gemm_bt_mfma<2><<<dim3(DI / 128, 1, KSPLIT), 256, 0, stream>>>(
      OpT + (size_t)DI * L_SEQ, L_SEQ, OpT, L_SEQ, Ppart, DI, L_SEQ, DI,
      nullptr, nullptr);

  // 5) reduce partials + transpose -> Ht (2048 x 128 bf16)
  h_reduce_t_kernel<<<128, 256, 0, stream>>>(Ppart, Ht);

  // 6) y = C @ Hcat + D*x_ssm : M=8192, N=2048, K=128, bf16 repacked out
  gemm_bt_mfma<1><<<dim3(DI / 128, L_SEQ / 128), 256, 0, stream>>>(
      cb, DS, Ht, DS, ybuf, DI, DS, DI, xs, D_param);

  // 7) LN + z-gate -> bf16 yz into zxb cols [2048,4096)
  ln_mul_kernel<<<L_SEQ, 256, 0, stream>>>(ybuf, zxb, ln_w, ln_b);

  // 8) out = yz @ W_out^T : M=8192, N=1024, K=2048
  //    256x128 v4 f32 out: grid 8 x 32 = 256 blocks
  gemm_v4<1><<<dim3(DM / 128, L_SEQ / 256), 512, 0, stream>>>(
      zxb + DI, DPROJ, wout_bf16, DI, out, DM, DI, DM);
}

// Round 9
// 323.762 us; speedup vs baseline: 1.0629x; 1.0158x over previous
//
#include <hip/hip_runtime.h>
#include <hip/hip_bf16.h>
#include <math.h>

#define L_SEQ 8192
#define DM 1024
#define DI 2048
#define NH 32
#define HD 64
#define DS 128
#define CDIM 2304
#define DPROJ 4384
#define NPAD_IN 4608  // 36*128, zero-padded W_in rows
#define KSPLIT 16
#define OPROWS 2176   // 2048 Vs^T rows + 128 B^T rows

typedef short bf16x8 __attribute__((ext_vector_type(8)));
typedef float floatx4 __attribute__((ext_vector_type(4)));
typedef unsigned short u16x4 __attribute__((ext_vector_type(4)));
typedef unsigned short u16x8 __attribute__((ext_vector_type(8)));

#define AS1(p) ((const __attribute__((address_space(1))) void*)(p))
#define AS3(p) ((__attribute__((address_space(3))) void*)(p))

__device__ __forceinline__ float bf2f(unsigned short u) {
  union { unsigned int i; float f; } c; c.i = ((unsigned int)u) << 16; return c.f;
}
__device__ __forceinline__ unsigned short f2bf(float f) {
  return __bfloat16_as_ushort(__float2bfloat16(f));
}

// ---------------------------------------------------------------------------
// 128x128-tile TLP bf16 GEMM (r5 structure — measured best: 87.1us on GEMM1,
// 888 TF intrinsic; the ~880 TF m97-family plateau). 2 blocks/CU without
// spilling: per-wave 64x32 out (acc[4][2]=32 VGPR, total ~52 measured).
// C[m,n] = sum_k A[m,k]*B[n,k]. 512 thr = 8 waves (2M x 4N), BK=64, NT=K/64
// (NT>=2 required). LDS 64 KB: A[2][128][64] + B[2][128][64] bf16 (16KB grps).
// Swizzle (rule #21 both-sides): byte ^= ((byte>>7)&7)<<4 within each 16KB
//   group; LDS dest LINEAR (gload_lds), involution on per-lane GLOBAL source
//   and again on ds_read addr. 2-way-only bank aliasing on ds_read_b128.
// Schedule per kt (buf=kt&1), 2 phases:
//   P1: read af(8)+b0(2); stage B[kt+1]->buf^1; bar; lgkm(0); prio1;
//       8 MFMA (ni=0); prio0; bar                      (no vm wait)
//   P2: read b1(2); stage A[kt+2]->buf; bar; lgkm(0); prio1;
//       8 MFMA (ni=1); prio0; vmcnt(2)|vmcnt(0); bar
// vmcnt ledger (2 instr per stage): prologue stages A0,B0,A1 (6 outst),
//   vmcnt(2) drains A0,B0. P1(kt): +B[kt+1] -> 4. P2(kt): +A[kt+2] -> 6;
//   end-P2 vmcnt(2) drains oldest 4 = {A,B}[kt+1] = P1(kt+1)'s inputs.
//   Tail: pfA false -> no stage, vmcnt(0). NT=2 (K=128) works: no P2 stage,
//   P1(0) stages B1, both tail waits vmcnt(0).
// OMODE 0: bf16 out via LDS repack (32KB), Nstore guard (8-col runs).
// OMODE 1: f32 out, direct frag stores (16-lane 64B segments).
// OMODE 2: bf16 out via LDS repack + fused D-add: C = bf16(v + Dvec[gcol>>6]
//   * xs[grow][gcol])  (GEMM6: y = C@Hcat + D*x_ssm; math order identical to
//   the old gemm_bt_mfma<1> epilogue).
// ---------------------------------------------------------------------------
template <int OMODE>
__global__ __launch_bounds__(512, 4)
void gemm128_tlp(const unsigned short* __restrict__ A, int lda,
                 const unsigned short* __restrict__ B, int ldb,
                 void* __restrict__ Cout, int ldc,
                 int K, int Nstore,
                 const unsigned short* __restrict__ xs,
                 const float* __restrict__ Dvec) {
  __shared__ __align__(16) char lds[65536];
  const int t = threadIdx.x;
  const int lane = t & 63;
  const int w = t >> 6;
  const int wm = w & 1, wn = w >> 1;
  const int fr = lane & 15, quad = lane >> 4;

  // bijective XCD swizzle: xcd owns a contiguous m-band, m-fastest within n
  int gx = gridDim.x, gy = gridDim.y;
  int linear = blockIdx.y * gx + blockIdx.x;
  int xcd = linear & 7, loc = linear >> 3;
  int mper = gy >> 3;                       // gy must be %8==0 (64 here)
  int mt = xcd * mper + loc % mper;
  int nt = loc / mper;
  const int m0 = mt << 7, n0 = nt << 7;
  const int NT = K >> 6;

  floatx4 acc[4][2];
#pragma unroll
  for (int i = 0; i < 4; ++i)
#pragma unroll
    for (int j = 0; j < 2; ++j) acc[i][j] = (floatx4){0.f, 0.f, 0.f, 0.f};
  bf16x8 af[4][2], b0[2], b1[2];

  // ---- staging: linear LDS dest, inverse-swizzled per-lane global source
  auto stA = [&](int buf, int kt) {
#pragma unroll
    for (int i = 0; i < 2; ++i) {
      int o = (i * 512 + t) * 16;                 // linear byte off in 16KB grp
      int os = o ^ (((o >> 7) & 7) << 4);         // element that lands here
      int rloc = os >> 7, kb = os & 127;
      const unsigned short* src = A + (size_t)(m0 + rloc) * lda + (kt << 6) + (kb >> 1);
      __builtin_amdgcn_global_load_lds(AS1(src), AS3(lds + buf * 16384 + o), 16, 0, 0);
    }
  };
  auto stB = [&](int buf, int kt) {
#pragma unroll
    for (int i = 0; i < 2; ++i) {
      int o = (i * 512 + t) * 16;
      int os = o ^ (((o >> 7) & 7) << 4);
      int rloc = os >> 7, kb = os & 127;
      const unsigned short* src = B + (size_t)(n0 + rloc) * ldb + (kt << 6) + (kb >> 1);
      __builtin_amdgcn_global_load_lds(AS1(src),
          AS3(lds + 32768 + buf * 16384 + o), 16, 0, 0);
    }
  };
  // ---- swizzled fragment reads
  auto rdA = [&](int buf, int mi, int ks) -> bf16x8 {
    int rloc = (wm << 6) | (mi << 4) | fr;
    return *(const bf16x8*)(lds + buf * 16384 + rloc * 128 +
                            (((ks << 6) | (quad << 4)) ^ ((fr & 7) << 4)));
  };
  auto rdB = [&](int buf, int ni, int ks) -> bf16x8 {
    int rloc = (wn << 5) | (ni << 4) | fr;
    return *(const bf16x8*)(lds + 32768 + buf * 16384 + rloc * 128 +
                            (((ks << 6) | (quad << 4)) ^ ((fr & 7) << 4)));
  };

  // ---- prologue: A0,B0 + A1; B1 staged inside P1(0)
  stA(0, 0); stB(0, 0);
  if (NT > 1) {
    stA(1, 1);
    asm volatile("s_waitcnt vmcnt(2)" ::: "memory");   // A0,B0 landed
  } else {
    asm volatile("s_waitcnt vmcnt(0)" ::: "memory");
  }
  __builtin_amdgcn_s_barrier();

  for (int kt = 0; kt < NT; ++kt) {
    const int buf = kt & 1;
    const bool pfB = (kt + 1 < NT);
    const bool pfA = (kt + 2 < NT);
    // ---------------- phase 1 (ni = 0) ----------------
#pragma unroll
    for (int mi = 0; mi < 4; ++mi) { af[mi][0] = rdA(buf, mi, 0); af[mi][1] = rdA(buf, mi, 1); }
    b0[0] = rdB(buf, 0, 0); b0[1] = rdB(buf, 0, 1);
    if (pfB) stB(buf ^ 1, kt + 1);
    __builtin_amdgcn_s_barrier();
    asm volatile("s_waitcnt lgkmcnt(0)" ::: "memory");
    __builtin_amdgcn_s_setprio(1);
#pragma unroll
    for (int mi = 0; mi < 4; ++mi)
#pragma unroll
      for (int ks = 0; ks < 2; ++ks)
        acc[mi][0] = __builtin_amdgcn_mfma_f32_16x16x32_bf16(af[mi][ks], b0[ks], acc[mi][0], 0, 0, 0);
    __builtin_amdgcn_s_setprio(0);
    __builtin_amdgcn_s_barrier();
    // ---------------- phase 2 (ni = 1) ----------------
    b1[0] = rdB(buf, 1, 0); b1[1] = rdB(buf, 1, 1);
    if (pfA) stA(buf, kt + 2);
    __builtin_amdgcn_s_barrier();
    asm volatile("s_waitcnt lgkmcnt(0)" ::: "memory");
    __builtin_amdgcn_s_setprio(1);
#pragma unroll
    for (int mi = 0; mi < 4; ++mi)
#pragma unroll
      for (int ks = 0; ks < 2; ++ks)
        acc[mi][1] = __builtin_amdgcn_mfma_f32_16x16x32_bf16(af[mi][ks], b1[ks], acc[mi][1], 0, 0, 0);
    __builtin_amdgcn_s_setprio(0);
    if (kt < NT - 1) {
      if (pfA) asm volatile("s_waitcnt vmcnt(2)" ::: "memory");  // {A,B}[kt+1]
      else     asm volatile("s_waitcnt vmcnt(0)" ::: "memory");
      __builtin_amdgcn_s_barrier();
    }
  }

  if (OMODE == 0 || OMODE == 2) {
    // ---- epilogue: repack 128x128 bf16 through LDS, full-line stores
    __syncthreads();                   // all LDS reads done before reuse
    unsigned short* rp = (unsigned short*)lds;
    unsigned short* C = (unsigned short*)Cout;
    const int mb = wm * 64, nb = wn * 32;
#pragma unroll
    for (int mi = 0; mi < 4; ++mi)
#pragma unroll
      for (int ni = 0; ni < 2; ++ni)
#pragma unroll
        for (int r = 0; r < 4; ++r)
          rp[(mb + mi * 16 + quad * 4 + r) * 128 + nb + ni * 16 + fr] = f2bf(acc[mi][ni][r]);
    __syncthreads();
#pragma unroll
    for (int j = 0; j < 4; ++j) {
      int lin = j * 4096 + t * 8;
      int row = lin >> 7, col = lin & 127;
      int grow = m0 + row;
      int gcol = n0 + col;
      u16x8 v = *(const u16x8*)&rp[lin];
      if (OMODE == 2) {
        u16x8 xv = *(const u16x8*)&xs[(size_t)grow * ldc + gcol];
        float Dh = Dvec[gcol >> 6];
        u16x8 o;
#pragma unroll
        for (int e = 0; e < 8; ++e) o[e] = f2bf(bf2f(v[e]) + Dh * bf2f(xv[e]));
        *(u16x8*)&C[(size_t)grow * ldc + gcol] = o;
      } else {
        if (gcol < Nstore)
          *(u16x8*)&C[(size_t)grow * ldc + gcol] = v;
      }
    }
  } else {
    // ---- f32 direct frag stores: 16 consecutive lanes -> 64B segments
    float* Cf = (float*)Cout;
#pragma unroll
    for (int mi = 0; mi < 4; ++mi)
#pragma unroll
      for (int ni = 0; ni < 2; ++ni) {
        int gcol = n0 + wn * 32 + ni * 16 + fr;
        int grow = m0 + wm * 64 + mi * 16 + quad * 4;
#pragma unroll
        for (int r = 0; r < 4; ++r)
          if (gcol < Nstore)
            Cf[(size_t)(grow + r) * ldc + gcol] = acc[mi][ni][r];
      }
  }
}

// ---------------------------------------------------------------------------
// bf16 MFMA GEMM: C[m,n] = sum_k A[m,k]*B[n,k]  (K contiguous both operands)
// 128x128 tile, BK=32, 4 waves (2x2), 4x4 frags of 16x16x32 each.
// (Retained for MODE 2: split-K SSM-state GEMM.)
// ---------------------------------------------------------------------------
template <int MODE>
__global__ __launch_bounds__(256)
void gemm_bt_mfma(const unsigned short* __restrict__ A, int lda,
                  const unsigned short* __restrict__ B, int ldb,
                  void* __restrict__ Cout, int ldc,
                  int Kfull, int Nstore,
                  const unsigned short* __restrict__ xs,
                  const float* __restrict__ Dvec) {
  __shared__ __align__(16) char smem[17408];  // staging 16 KB; f32 repack 17 KB
  unsigned short* Asm = (unsigned short*)smem;
  unsigned short* Bsm = Asm + 128 * 32;
  const int t = threadIdx.x;

  int bx = blockIdx.x, by = blockIdx.y;
  if (MODE != 2) {
    int gx = gridDim.x;
    int linear = by * gx + bx;
    int xcd = linear & 7;
    int local = linear >> 3;
    by = xcd * 8 + (local & 7);
    bx = local >> 3;
  }
  const int m0 = by * 128;
  const int n0 = bx * 128;

  int kstart = 0, klen = Kfull;
  if (MODE == 2) { klen = Kfull / KSPLIT; kstart = blockIdx.z * klen; }
  const int wave = t >> 6, lane = t & 63;
  const int wm = (wave & 1) * 64;
  const int wn = (wave >> 1) * 64;
  const int fr = lane & 15;
  const int quad = lane >> 4;

  floatx4 acc[4][4];
#pragma unroll
  for (int i = 0; i < 4; ++i)
#pragma unroll
    for (int j = 0; j < 4; ++j) acc[i][j] = (floatx4){0.f, 0.f, 0.f, 0.f};

  for (int k0 = kstart; k0 < kstart + klen; k0 += 32) {
#pragma unroll
    for (int i = 0; i < 2; ++i) {
      int linear = i * 256 + t;          // 0..511
      int row = linear >> 2;             // 0..127
      int kq = (linear & 3) * 8;         // bf16 elem offset in K
      const unsigned short* ga = A + (size_t)(m0 + row) * lda + (k0 + kq);
      const unsigned short* gb = B + (size_t)(n0 + row) * ldb + (k0 + kq);
      __builtin_amdgcn_global_load_lds(AS1(ga), AS3(&Asm[linear * 8]), 16, 0, 0);
      __builtin_amdgcn_global_load_lds(AS1(gb), AS3(&Bsm[linear * 8]), 16, 0, 0);
    }
    __syncthreads();

    bf16x8 af[4], bfr[4];
#pragma unroll
    for (int i = 0; i < 4; ++i) {
      af[i]  = *(const bf16x8*)&Asm[(wm + i * 16 + fr) * 32 + quad * 8];
      bfr[i] = *(const bf16x8*)&Bsm[(wn + i * 16 + fr) * 32 + quad * 8];
    }
#pragma unroll
    for (int mi = 0; mi < 4; ++mi)
#pragma unroll
      for (int ni = 0; ni < 4; ++ni)
        acc[mi][ni] = __builtin_amdgcn_mfma_f32_16x16x32_bf16(
            af[mi], bfr[ni], acc[mi][ni], 0, 0, 0);
    __syncthreads();
  }

  // C/D frag layout: col = lane&15, row = (lane>>4)*4 + r  [m89-verified]
  const int lrbase = (wm ? 16 : 0) + quad * 4;
  {
    float(*rpf)[136] = (float(*)[136])smem;  // 32*136*4 = 17408 B
    float* C = (float*)Cout;
    if (MODE == 2) C += (size_t)blockIdx.z * DS * DI;
#pragma unroll
    for (int mi = 0; mi < 4; ++mi) {
      __syncthreads();
#pragma unroll
      for (int ni = 0; ni < 4; ++ni)
#pragma unroll
        for (int r = 0; r < 4; ++r)
          rpf[lrbase + r][wn + ni * 16 + fr] = acc[mi][ni][r];
      __syncthreads();
#pragma unroll
      for (int j = 0; j < 4; ++j) {
        int off = j * 1024 + t * 4;          // elem in 32x128 group
        int lr = off >> 7, c = off & 127;
        int grow = m0 + (lr >> 4) * 64 + mi * 16 + (lr & 15);
        int gcol = n0 + c;
        float4 v = *(const float4*)&rpf[lr][c];
        *(float4*)&C[(size_t)grow * ldc + gcol] = v;
      }
    }
  }
}

// ---------------------------------------------------------------------------
// One merged cast dispatch. Regions (in 256-thread blocks of 4-elem quads):
//   [0, 8192):        x       (8192x1024 f32 -> bf16)
//   [8192, 12800):    W_in    (4384x1024 -> 4608x1024 bf16, pad rows zero)
//   [12800, 14848):   W_out   (1024x2048 f32 -> bf16)
// ---------------------------------------------------------------------------
__global__ __launch_bounds__(256)
void cast_all_kernel(const float* __restrict__ x, const float* __restrict__ W_in,
                     const float* __restrict__ W_out,
                     unsigned short* __restrict__ x_bf16,
                     unsigned short* __restrict__ win_bf16,
                     unsigned short* __restrict__ wout_bf16) {
  int b = blockIdx.x;
  int t = threadIdx.x;
  u16x4 o = (u16x4){0, 0, 0, 0};
  if (b < 8192) {
    size_t i4 = ((size_t)b * 256 + t) * 4;
    float4 v = *(const float4*)(x + i4);
    o.x = f2bf(v.x); o.y = f2bf(v.y); o.z = f2bf(v.z); o.w = f2bf(v.w);
    *(u16x4*)(x_bf16 + i4) = o;
  } else if (b < 12800) {
    size_t i4 = ((size_t)(b - 8192) * 256 + t) * 4;  // over 4608*1024
    int row = (int)(i4 >> 10);
    if (row < DPROJ) {
      float4 v = *(const float4*)(W_in + i4);
      o.x = f2bf(v.x); o.y = f2bf(v.y); o.z = f2bf(v.z); o.w = f2bf(v.w);
    }
    *(u16x4*)(win_bf16 + i4) = o;
  } else {
    size_t i4 = ((size_t)(b - 12800) * 256 + t) * 4;
    float4 v = *(const float4*)(W_out + i4);
    o.x = f2bf(v.x); o.y = f2bf(v.y); o.z = f2bf(v.z); o.w = f2bf(v.w);
    *(u16x4*)(wout_bf16 + i4) = o;
  }
}

// ---------------------------------------------------------------------------
// s[l,h] = dt * exp(-dt*exp(A_log[h])),  dt = softplus(zxb[l,4352+h]+dt_bias[h])
// ---------------------------------------------------------------------------
__global__ __launch_bounds__(256)
void dt_kernel(const unsigned short* __restrict__ zxb, const float* __restrict__ dt_bias,
               const float* __restrict__ A_log, float* __restrict__ s_out) {
  int idx = blockIdx.x * 256 + threadIdx.x;  // l*32 + h
  int l = idx >> 5, h = idx & 31;
  float v = bf2f(zxb[(size_t)l * DPROJ + (DI + CDIM) + h]) + dt_bias[h];
  float d = (v > 20.f) ? v : log1pf(expf(v));
  s_out[idx] = d * expf(-d * expf(A_log[h]));
}

// ---------------------------------------------------------------------------
// Fused conv+silu+transpose. Block = 64 channels x 64 l, 256 threads.
// ---------------------------------------------------------------------------
__global__ __launch_bounds__(256)
void conv_fused_kernel(const unsigned short* __restrict__ zxb,
                       const float* __restrict__ Wc,
                       const float* __restrict__ bc,
                       const float* __restrict__ svec,
                       unsigned short* __restrict__ xs,
                       unsigned short* __restrict__ cb,
                       unsigned short* __restrict__ OpT) {
  __shared__ unsigned short zt[67][66];
  __shared__ unsigned short ot[64][66];
  __shared__ float sl[64];
  const int c0 = blockIdx.x * 64;
  const int l0 = blockIdx.y * 64;
  const int t = threadIdx.x;
  for (int idx = t; idx < 67 * 16; idx += 256) {
    int row = idx >> 4;
    int colq = (idx & 15) * 4;
    int gl = l0 - 1 + row;
    u16x4 v = (u16x4){0, 0, 0, 0};
    if (gl >= 0 && gl < L_SEQ)
      v = *(const u16x4*)&zxb[(size_t)gl * DPROJ + DI + c0 + colq];
    *(u16x4*)&zt[row][colq] = v;
  }
  const bool isX = (c0 < DI);
  const bool isC = (c0 >= DI + DS);
  if (isX && t < 64) sl[t] = svec[(size_t)(l0 + t) * NH + (c0 >> 6)];
  const int c = t & 63;
  const int gc = c0 + c;
  const float4 wv = *(const float4*)&Wc[gc * 4];
  const float bias = bc[gc];
  const int lq = (t >> 6) * 16;
  __syncthreads();
#pragma unroll
  for (int i = 0; i < 16; ++i) {
    int ll = lq + i;
    float sacc = bias + bf2f(zt[ll][c]) * wv.x + bf2f(zt[ll + 1][c]) * wv.y +
                 bf2f(zt[ll + 2][c]) * wv.z + bf2f(zt[ll + 3][c]) * wv.w;
    float v = sacc / (1.f + expf(-sacc));
    int gl = l0 + ll;
    if (isC) {
      cb[(size_t)gl * DS + (gc - (DI + DS))] = f2bf(v);
    } else if (isX) {
      xs[(size_t)gl * DI + gc] = f2bf(v);
      ot[c][ll] = f2bf(v * sl[ll]);
    } else {
      ot[c][ll] = f2bf(v);
    }
  }
  if (!isC) {
    __syncthreads();
#pragma unroll
    for (int j = 0; j < 4; ++j) {
      int linear = j * 1024 + t * 4;
      int rr = linear >> 6;
      int lc = linear & 63;
      *(u16x4*)&OpT[(size_t)(c0 + rr) * L_SEQ + l0 + lc] = *(const u16x4*)&ot[rr][lc];
    }
  }
}

// ---------------------------------------------------------------------------
// Ht[p][n] = bf16( sum_z Ppart[z][n][p] )
// ---------------------------------------------------------------------------
__global__ __launch_bounds__(256)
void h_reduce_t_kernel(const float* __restrict__ P, unsigned short* __restrict__ Ht) {
  __shared__ float tile[32][65];
  const int bid = blockIdx.x;
  const int pt = bid & 31, ng = bid >> 5;
  const int t = threadIdx.x;
#pragma unroll
  for (int i = 0; i < 8; ++i) {
    int nl = i * 4 + (t >> 6);
    int n = ng * 32 + nl;
    int p = pt * 64 + (t & 63);
    float acc = 0.f;
#pragma unroll
    for (int z = 0; z < KSPLIT; ++z)
      acc += P[(size_t)z * (DS * DI) + (size_t)n * DI + p];
    tile[nl][t & 63] = acc;
  }
  __syncthreads();
#pragma unroll
  for (int j = 0; j < 8; ++j) {
    int linear = j * 256 + t;
    int pl = linear >> 5, nl = linear & 31;
    Ht[(size_t)(pt * 64 + pl) * DS + ng * 32 + nl] = f2bf(tile[nl][pl]);
  }
}

// ---------------------------------------------------------------------------
// LayerNorm over 2048 (bf16 y) + z-gate (bf16 z); bf16 yz into zxb [2048,4096)
// ---------------------------------------------------------------------------
__global__ __launch_bounds__(256)
void ln_mul_kernel(const unsigned short* __restrict__ ybuf, unsigned short* __restrict__ zxb,
                   const float* __restrict__ ln_w, const float* __restrict__ ln_b) {
  int l = blockIdx.x;
  int t = threadIdx.x;
  int c0 = t * 8;
  u16x8 yv = *(const u16x8*)&ybuf[(size_t)l * DI + c0];
  float vals[8];
  float s = 0.f, sq = 0.f;
#pragma unroll
  for (int i = 0; i < 8; ++i) {
    float v = bf2f(yv[i]);
    vals[i] = v;
    s += v;
    sq += v * v;
  }
#pragma unroll
  for (int off = 32; off > 0; off >>= 1) {
    s += __shfl_down(s, off, 64);
    sq += __shfl_down(sq, off, 64);
  }
  __shared__ float red[10];
  int wave = t >> 6, lane = t & 63;
  if (lane == 0) { red[wave] = s; red[4 + wave] = sq; }
  __syncthreads();
  if (t == 0) {
    float S = red[0] + red[1] + red[2] + red[3];
    float SQ = red[4] + red[5] + red[6] + red[7];
    float mu = S / (float)DI;
    red[8] = mu;
    red[9] = rsqrtf(SQ / (float)DI - mu * mu + 1e-5f);
  }
  __syncthreads();
  float mu = red[8], rstd = red[9];
  unsigned short* zrow = zxb + (size_t)l * DPROJ;
  u16x8 zv = *(const u16x8*)&zrow[c0];
  float4 w0 = *(const float4*)&ln_w[c0], w1 = *(const float4*)&ln_w[c0 + 4];
  float4 b0 = *(const float4*)&ln_b[c0], b1 = *(const float4*)&ln_b[c0 + 4];
  float w[8] = {w0.x, w0.y, w0.z, w0.w, w1.x, w1.y, w1.z, w1.w};
  float b[8] = {b0.x, b0.y, b0.z, b0.w, b1.x, b1.y, b1.z, b1.w};
  u16x8 o;
#pragma unroll
  for (int i = 0; i < 8; ++i) {
    float v = (vals[i] - mu) * rstd * w[i] + b[i];
    o[i] = f2bf(v * bf2f(zv[i]));
  }
  *(u16x8*)&zrow[DI + c0] = o;
}

// ---------------------------------------------------------------------------
extern "C" void kernel_launch(void* const* d_in, const int* in_sizes, int n_in,
                              void* d_out, int out_size, void* d_ws, size_t ws_size,
                              hipStream_t stream) {
  const float* x       = (const float*)d_in[0];
  const float* W_in    = (const float*)d_in[1];
  const float* W_conv  = (const float*)d_in[2];
  const float* b_conv  = (const float*)d_in[3];
  const float* dt_bias = (const float*)d_in[4];
  const float* A_log   = (const float*)d_in[5];
  const float* D_param = (const float*)d_in[6];
  const float* ln_w    = (const float*)d_in[7];
  const float* ln_b    = (const float*)d_in[8];
  const float* W_out   = (const float*)d_in[9];
  float* out = (float*)d_out;

  // ---- workspace layout ----
  unsigned short* zxb = (unsigned short*)d_ws;           // L*4384 bf16
  unsigned short* xs   = zxb + (size_t)L_SEQ * DPROJ;    // L*2048 bf16
  unsigned short* cb   = xs + (size_t)L_SEQ * DI;        // L*128 bf16
  float* svec = (float*)(cb + (size_t)L_SEQ * DS);       // L*32 f32
  unsigned short* OpT = (unsigned short*)(svec + (size_t)L_SEQ * NH);  // 2176*8192 bf16
  float* Ppart = (float*)(OpT + (size_t)OPROWS * L_SEQ); // KSPLIT*128*2048 f32
  unsigned short* Ht = (unsigned short*)(Ppart + (size_t)KSPLIT * DS * DI);  // 2048*128
  unsigned short* wout_bf16 = Ht + (size_t)DI * DS;      // 1024*2048 bf16
  // aliases in OpT's dead windows:
  unsigned short* x_bf16   = OpT;                        // casts..GEMM1 (16 MB)
  unsigned short* win_bf16 = OpT + (size_t)L_SEQ * DM;   // casts..GEMM1 (9.4 MB)
  unsigned short* ybuf     = OpT;                        // Y-GEMM..ln_mul (33.5 MB)

  // 0) all casts in one dispatch
  cast_all_kernel<<<14848, 256, 0, stream>>>(x, W_in, W_out, x_bf16, win_bf16,
                                             wout_bf16);

  // 1) zxb = bf16( x @ W_in^T )  (M=8192, N=4608 pad, K=1024)
  //    128x128 TLP (r5 structure, measured best); grid 36x64, 2 blocks/CU
  gemm128_tlp<0><<<dim3(NPAD_IN / 128, L_SEQ / 128), 512, 0, stream>>>(
      x_bf16, DM, win_bf16, DM, zxb, DPROJ, DM, DPROJ, nullptr, nullptr);

  // 2) s = a*dt
  dt_kernel<<<(L_SEQ * NH) / 256, 256, 0, stream>>>(zxb, dt_bias, A_log, svec);

  // 3) conv + silu + transpose-pack (clobbers x_bf16/win_bf16 — dead)
  conv_fused_kernel<<<dim3(CDIM / 64, L_SEQ / 64), 256, 0, stream>>>(
      zxb, W_conv, b_conv, svec, xs, cb, OpT);

  // 4) Hcat = B^T @ Vs : M=128, N=2048, K=8192, split-K=16 (256 blocks, f32 out)
  gemm_bt_mfma<2><<<dim3(DI / 128, 1, KSPLIT), 256, 0, stream>>>(
      OpT + (size_t)DI * L_SEQ, L_SEQ, OpT, L_SEQ, Ppart, DI, L_SEQ, DI,
      nullptr, nullptr);

  // 5) reduce partials + transpose -> Ht (2048 x 128 bf16)
  h_reduce_t_kernel<<<128, 256, 0, stream>>>(Ppart, Ht);

  // 6) y = C @ Hcat + D*x_ssm : M=8192, N=2048, K=128 -> tlp OMODE 2
  //    (NT=2 ring; fused D-add epilogue; grid 16x64, 2 blocks/CU)
  gemm128_tlp<2><<<dim3(DI / 128, L_SEQ / 128), 512, 0, stream>>>(
      cb, DS, Ht, DS, ybuf, DI, DS, DI, xs, D_param);

  // 7) LN + z-gate -> bf16 yz into zxb cols [2048,4096)
  ln_mul_kernel<<<L_SEQ, 256, 0, stream>>>(ybuf, zxb, ln_w, ln_b);

  // 8) out = yz @ W_out^T : M=8192, N=1024, K=2048
  //    128x128 TLP f32 out: grid 8x64 = 512 blocks, 2 blocks/CU, 1 round
  gemm128_tlp<1><<<dim3(DM / 128, L_SEQ / 128), 512, 0, stream>>>(
      zxb + DI, DPROJ, wout_bf16, DI, out, DM, DI, DM, nullptr, nullptr);
}

// Round 11
// 318.659 us; speedup vs baseline: 1.0800x; 1.0160x over previous
//
#include <hip/hip_runtime.h>
#include <hip/hip_bf16.h>
#include <math.h>

#define L_SEQ 8192
#define DM 1024
#define DI 2048
#define NH 32
#define HD 64
#define DS 128
#define CDIM 2304
#define DPROJ 4384
#define NPAD_IN 4608  // 36*128, zero-padded W_in rows
#define KSPLIT 16
#define OPROWS 2176   // 2048 Vs^T rows + 128 B^T rows

typedef short bf16x8 __attribute__((ext_vector_type(8)));
typedef float floatx4 __attribute__((ext_vector_type(4)));
typedef unsigned short u16x4 __attribute__((ext_vector_type(4)));
typedef unsigned short u16x8 __attribute__((ext_vector_type(8)));

#define AS1(p) ((const __attribute__((address_space(1))) void*)(p))
#define AS3(p) ((__attribute__((address_space(3))) void*)(p))

__device__ __forceinline__ float bf2f(unsigned short u) {
  union { unsigned int i; float f; } c; c.i = ((unsigned int)u) << 16; return c.f;
}
__device__ __forceinline__ unsigned short f2bf(float f) {
  return __bfloat16_as_ushort(__float2bfloat16(f));
}

// ---------------------------------------------------------------------------
// 128x128-tile TLP bf16 GEMM (r5 structure — measured best: 88.8us on GEMM1,
// 888 TF; the ~880 TF m97-family plateau, geometry-locked per r9 analysis).
// 2 blocks/CU without spilling: per-wave 64x32 out (acc[4][2]=32 VGPR).
// C[m,n] = sum_k A[m,k]*B[n,k]. 512 thr = 8 waves (2M x 4N), BK=64, NT=K/64
// (NT>=2 required). LDS 64 KB: A[2][128][64] + B[2][128][64] bf16 (16KB grps).
// Swizzle (rule #21 both-sides): byte ^= ((byte>>7)&7)<<4 within each 16KB
//   group; LDS dest LINEAR (gload_lds), involution on per-lane GLOBAL source
//   and again on ds_read addr. 2-way-only bank aliasing on ds_read_b128.
// Schedule per kt (buf=kt&1), 2 phases:
//   P1: read af(8)+b0(2); stage B[kt+1]->buf^1; bar; lgkm(0); prio1;
//       8 MFMA (ni=0); prio0; bar                      (no vm wait)
//   P2: read b1(2); stage A[kt+2]->buf; bar; lgkm(0); prio1;
//       8 MFMA (ni=1); prio0; vmcnt(2)|vmcnt(0); bar
// vmcnt ledger (2 instr per stage): prologue stages A0,B0,A1 (6 outst),
//   vmcnt(2) drains A0,B0. P1(kt): +B[kt+1] -> 4. P2(kt): +A[kt+2] -> 6;
//   end-P2 vmcnt(2) drains oldest 4 = {A,B}[kt+1] = P1(kt+1)'s inputs.
//   Tail: pfA false -> no stage, vmcnt(0). NT=2 (K=128) works: no P2 stage,
//   P1(0) stages B1, both tail waits vmcnt(0).
// OMODE 0: bf16 out via LDS repack (32KB), Nstore guard (8-col runs).
// OMODE 1: f32 out, direct frag stores (16-lane 64B segments).
// OMODE 2: bf16 out via LDS repack + fused D-add (GEMM6).
// ---------------------------------------------------------------------------
template <int OMODE>
__global__ __launch_bounds__(512, 4)
void gemm128_tlp(const unsigned short* __restrict__ A, int lda,
                 const unsigned short* __restrict__ B, int ldb,
                 void* __restrict__ Cout, int ldc,
                 int K, int Nstore,
                 const unsigned short* __restrict__ xs,
                 const float* __restrict__ Dvec) {
  __shared__ __align__(16) char lds[65536];
  const int t = threadIdx.x;
  const int lane = t & 63;
  const int w = t >> 6;
  const int wm = w & 1, wn = w >> 1;
  const int fr = lane & 15, quad = lane >> 4;

  // bijective XCD swizzle: xcd owns a contiguous m-band, m-fastest within n
  int gx = gridDim.x, gy = gridDim.y;
  int linear = blockIdx.y * gx + blockIdx.x;
  int xcd = linear & 7, loc = linear >> 3;
  int mper = gy >> 3;                       // gy must be %8==0 (64 here)
  int mt = xcd * mper + loc % mper;
  int nt = loc / mper;
  const int m0 = mt << 7, n0 = nt << 7;
  const int NT = K >> 6;

  floatx4 acc[4][2];
#pragma unroll
  for (int i = 0; i < 4; ++i)
#pragma unroll
    for (int j = 0; j < 2; ++j) acc[i][j] = (floatx4){0.f, 0.f, 0.f, 0.f};
  bf16x8 af[4][2], b0[2], b1[2];

  // ---- staging: linear LDS dest, inverse-swizzled per-lane global source
  auto stA = [&](int buf, int kt) {
#pragma unroll
    for (int i = 0; i < 2; ++i) {
      int o = (i * 512 + t) * 16;                 // linear byte off in 16KB grp
      int os = o ^ (((o >> 7) & 7) << 4);         // element that lands here
      int rloc = os >> 7, kb = os & 127;
      const unsigned short* src = A + (size_t)(m0 + rloc) * lda + (kt << 6) + (kb >> 1);
      __builtin_amdgcn_global_load_lds(AS1(src), AS3(lds + buf * 16384 + o), 16, 0, 0);
    }
  };
  auto stB = [&](int buf, int kt) {
#pragma unroll
    for (int i = 0; i < 2; ++i) {
      int o = (i * 512 + t) * 16;
      int os = o ^ (((o >> 7) & 7) << 4);
      int rloc = os >> 7, kb = os & 127;
      const unsigned short* src = B + (size_t)(n0 + rloc) * ldb + (kt << 6) + (kb >> 1);
      __builtin_amdgcn_global_load_lds(AS1(src),
          AS3(lds + 32768 + buf * 16384 + o), 16, 0, 0);
    }
  };
  // ---- swizzled fragment reads
  auto rdA = [&](int buf, int mi, int ks) -> bf16x8 {
    int rloc = (wm << 6) | (mi << 4) | fr;
    return *(const bf16x8*)(lds + buf * 16384 + rloc * 128 +
                            (((ks << 6) | (quad << 4)) ^ ((fr & 7) << 4)));
  };
  auto rdB = [&](int buf, int ni, int ks) -> bf16x8 {
    int rloc = (wn << 5) | (ni << 4) | fr;
    return *(const bf16x8*)(lds + 32768 + buf * 16384 + rloc * 128 +
                            (((ks << 6) | (quad << 4)) ^ ((fr & 7) << 4)));
  };

  // ---- prologue: A0,B0 + A1; B1 staged inside P1(0)
  stA(0, 0); stB(0, 0);
  if (NT > 1) {
    stA(1, 1);
    asm volatile("s_waitcnt vmcnt(2)" ::: "memory");   // A0,B0 landed
  } else {
    asm volatile("s_waitcnt vmcnt(0)" ::: "memory");
  }
  __builtin_amdgcn_s_barrier();

  for (int kt = 0; kt < NT; ++kt) {
    const int buf = kt & 1;
    const bool pfB = (kt + 1 < NT);
    const bool pfA = (kt + 2 < NT);
    // ---------------- phase 1 (ni = 0) ----------------
#pragma unroll
    for (int mi = 0; mi < 4; ++mi) { af[mi][0] = rdA(buf, mi, 0); af[mi][1] = rdA(buf, mi, 1); }
    b0[0] = rdB(buf, 0, 0); b0[1] = rdB(buf, 0, 1);
    if (pfB) stB(buf ^ 1, kt + 1);
    __builtin_amdgcn_s_barrier();
    asm volatile("s_waitcnt lgkmcnt(0)" ::: "memory");
    __builtin_amdgcn_s_setprio(1);
#pragma unroll
    for (int mi = 0; mi < 4; ++mi)
#pragma unroll
      for (int ks = 0; ks < 2; ++ks)
        acc[mi][0] = __builtin_amdgcn_mfma_f32_16x16x32_bf16(af[mi][ks], b0[ks], acc[mi][0], 0, 0, 0);
    __builtin_amdgcn_s_setprio(0);
    __builtin_amdgcn_s_barrier();
    // ---------------- phase 2 (ni = 1) ----------------
    b1[0] = rdB(buf, 1, 0); b1[1] = rdB(buf, 1, 1);
    if (pfA) stA(buf, kt + 2);
    __builtin_amdgcn_s_barrier();
    asm volatile("s_waitcnt lgkmcnt(0)" ::: "memory");
    __builtin_amdgcn_s_setprio(1);
#pragma unroll
    for (int mi = 0; mi < 4; ++mi)
#pragma unroll
      for (int ks = 0; ks < 2; ++ks)
        acc[mi][1] = __builtin_amdgcn_mfma_f32_16x16x32_bf16(af[mi][ks], b1[ks], acc[mi][1], 0, 0, 0);
    __builtin_amdgcn_s_setprio(0);
    if (kt < NT - 1) {
      if (pfA) asm volatile("s_waitcnt vmcnt(2)" ::: "memory");  // {A,B}[kt+1]
      else     asm volatile("s_waitcnt vmcnt(0)" ::: "memory");
      __builtin_amdgcn_s_barrier();
    }
  }

  if (OMODE == 0 || OMODE == 2) {
    // ---- epilogue: repack 128x128 bf16 through LDS, full-line stores
    __syncthreads();                   // all LDS reads done before reuse
    unsigned short* rp = (unsigned short*)lds;
    unsigned short* C = (unsigned short*)Cout;
    const int mb = wm * 64, nb = wn * 32;
#pragma unroll
    for (int mi = 0; mi < 4; ++mi)
#pragma unroll
      for (int ni = 0; ni < 2; ++ni)
#pragma unroll
        for (int r = 0; r < 4; ++r)
          rp[(mb + mi * 16 + quad * 4 + r) * 128 + nb + ni * 16 + fr] = f2bf(acc[mi][ni][r]);
    __syncthreads();
#pragma unroll
    for (int j = 0; j < 4; ++j) {
      int lin = j * 4096 + t * 8;
      int row = lin >> 7, col = lin & 127;
      int grow = m0 + row;
      int gcol = n0 + col;
      u16x8 v = *(const u16x8*)&rp[lin];
      if (OMODE == 2) {
        u16x8 xv = *(const u16x8*)&xs[(size_t)grow * ldc + gcol];
        float Dh = Dvec[gcol >> 6];
        u16x8 o;
#pragma unroll
        for (int e = 0; e < 8; ++e) o[e] = f2bf(bf2f(v[e]) + Dh * bf2f(xv[e]));
        *(u16x8*)&C[(size_t)grow * ldc + gcol] = o;
      } else {
        if (gcol < Nstore)
          *(u16x8*)&C[(size_t)grow * ldc + gcol] = v;
      }
    }
  } else {
    // ---- f32 direct frag stores: 16 consecutive lanes -> 64B segments
    float* Cf = (float*)Cout;
#pragma unroll
    for (int mi = 0; mi < 4; ++mi)
#pragma unroll
      for (int ni = 0; ni < 2; ++ni) {
        int gcol = n0 + wn * 32 + ni * 16 + fr;
        int grow = m0 + wm * 64 + mi * 16 + quad * 4;
#pragma unroll
        for (int r = 0; r < 4; ++r)
          if (gcol < Nstore)
            Cf[(size_t)(grow + r) * ldc + gcol] = acc[mi][ni][r];
      }
  }
}

// ---------------------------------------------------------------------------
// bf16 MFMA GEMM: C[m,n] = sum_k A[m,k]*B[n,k]  (K contiguous both operands)
// 128x128 tile, BK=32, 4 waves (2x2), 4x4 frags of 16x16x32 each.
// (Retained for MODE 2: split-K SSM-state GEMM.)
// ---------------------------------------------------------------------------
template <int MODE>
__global__ __launch_bounds__(256)
void gemm_bt_mfma(const unsigned short* __restrict__ A, int lda,
                  const unsigned short* __restrict__ B, int ldb,
                  void* __restrict__ Cout, int ldc,
                  int Kfull, int Nstore,
                  const unsigned short* __restrict__ xs,
                  const float* __restrict__ Dvec) {
  __shared__ __align__(16) char smem[17408];  // staging 16 KB; f32 repack 17 KB
  unsigned short* Asm = (unsigned short*)smem;
  unsigned short* Bsm = Asm + 128 * 32;
  const int t = threadIdx.x;

  int bx = blockIdx.x, by = blockIdx.y;
  if (MODE != 2) {
    int gx = gridDim.x;
    int linear = by * gx + bx;
    int xcd = linear & 7;
    int local = linear >> 3;
    by = xcd * 8 + (local & 7);
    bx = local >> 3;
  }
  const int m0 = by * 128;
  const int n0 = bx * 128;

  int kstart = 0, klen = Kfull;
  if (MODE == 2) { klen = Kfull / KSPLIT; kstart = blockIdx.z * klen; }
  const int wave = t >> 6, lane = t & 63;
  const int wm = (wave & 1) * 64;
  const int wn = (wave >> 1) * 64;
  const int fr = lane & 15;
  const int quad = lane >> 4;

  floatx4 acc[4][4];
#pragma unroll
  for (int i = 0; i < 4; ++i)
#pragma unroll
    for (int j = 0; j < 4; ++j) acc[i][j] = (floatx4){0.f, 0.f, 0.f, 0.f};

  for (int k0 = kstart; k0 < kstart + klen; k0 += 32) {
#pragma unroll
    for (int i = 0; i < 2; ++i) {
      int linear = i * 256 + t;          // 0..511
      int row = linear >> 2;             // 0..127
      int kq = (linear & 3) * 8;         // bf16 elem offset in K
      const unsigned short* ga = A + (size_t)(m0 + row) * lda + (k0 + kq);
      const unsigned short* gb = B + (size_t)(n0 + row) * ldb + (k0 + kq);
      __builtin_amdgcn_global_load_lds(AS1(ga), AS3(&Asm[linear * 8]), 16, 0, 0);
      __builtin_amdgcn_global_load_lds(AS1(gb), AS3(&Bsm[linear * 8]), 16, 0, 0);
    }
    __syncthreads();

    bf16x8 af[4], bfr[4];
#pragma unroll
    for (int i = 0; i < 4; ++i) {
      af[i]  = *(const bf16x8*)&Asm[(wm + i * 16 + fr) * 32 + quad * 8];
      bfr[i] = *(const bf16x8*)&Bsm[(wn + i * 16 + fr) * 32 + quad * 8];
    }
#pragma unroll
    for (int mi = 0; mi < 4; ++mi)
#pragma unroll
      for (int ni = 0; ni < 4; ++ni)
        acc[mi][ni] = __builtin_amdgcn_mfma_f32_16x16x32_bf16(
            af[mi], bfr[ni], acc[mi][ni], 0, 0, 0);
    __syncthreads();
  }

  // C/D frag layout: col = lane&15, row = (lane>>4)*4 + r  [m89-verified]
  const int lrbase = (wm ? 16 : 0) + quad * 4;
  {
    float(*rpf)[136] = (float(*)[136])smem;  // 32*136*4 = 17408 B
    float* C = (float*)Cout;
    if (MODE == 2) C += (size_t)blockIdx.z * DS * DI;
#pragma unroll
    for (int mi = 0; mi < 4; ++mi) {
      __syncthreads();
#pragma unroll
      for (int ni = 0; ni < 4; ++ni)
#pragma unroll
        for (int r = 0; r < 4; ++r)
          rpf[lrbase + r][wn + ni * 16 + fr] = acc[mi][ni][r];
      __syncthreads();
#pragma unroll
      for (int j = 0; j < 4; ++j) {
        int off = j * 1024 + t * 4;          // elem in 32x128 group
        int lr = off >> 7, c = off & 127;
        int grow = m0 + (lr >> 4) * 64 + mi * 16 + (lr & 15);
        int gcol = n0 + c;
        float4 v = *(const float4*)&rpf[lr][c];
        *(float4*)&C[(size_t)grow * ldc + gcol] = v;
      }
    }
  }
}

// ---------------------------------------------------------------------------
// One merged cast dispatch. Regions (in 256-thread blocks of 4-elem quads):
//   [0, 8192):        x       (8192x1024 f32 -> bf16)
//   [8192, 12800):    W_in    (4384x1024 -> 4608x1024 bf16, pad rows zero)
//   [12800, 14848):   W_out   (1024x2048 f32 -> bf16)
// ---------------------------------------------------------------------------
__global__ __launch_bounds__(256)
void cast_all_kernel(const float* __restrict__ x, const float* __restrict__ W_in,
                     const float* __restrict__ W_out,
                     unsigned short* __restrict__ x_bf16,
                     unsigned short* __restrict__ win_bf16,
                     unsigned short* __restrict__ wout_bf16) {
  int b = blockIdx.x;
  int t = threadIdx.x;
  u16x4 o = (u16x4){0, 0, 0, 0};
  if (b < 8192) {
    size_t i4 = ((size_t)b * 256 + t) * 4;
    float4 v = *(const float4*)(x + i4);
    o.x = f2bf(v.x); o.y = f2bf(v.y); o.z = f2bf(v.z); o.w = f2bf(v.w);
    *(u16x4*)(x_bf16 + i4) = o;
  } else if (b < 12800) {
    size_t i4 = ((size_t)(b - 8192) * 256 + t) * 4;  // over 4608*1024
    int row = (int)(i4 >> 10);
    if (row < DPROJ) {
      float4 v = *(const float4*)(W_in + i4);
      o.x = f2bf(v.x); o.y = f2bf(v.y); o.z = f2bf(v.z); o.w = f2bf(v.w);
    }
    *(u16x4*)(win_bf16 + i4) = o;
  } else {
    size_t i4 = ((size_t)(b - 12800) * 256 + t) * 4;
    float4 v = *(const float4*)(W_out + i4);
    o.x = f2bf(v.x); o.y = f2bf(v.y); o.z = f2bf(v.z); o.w = f2bf(v.w);
    *(u16x4*)(wout_bf16 + i4) = o;
  }
}

// ---------------------------------------------------------------------------
// Fused conv+silu+transpose WITH dt fusion (r10). Block = 64 ch x 64 l,
// 256 threads = 8 channel-groups x 32 l (two l-halves).
// dt fusion: each isX block covers exactly one head h = c0>>6 (HD=64), so it
// computes its own sl[l] = dt*exp(-dt*exp(A_log[h])) from zxb dt-cols with
// bit-identical math to the old dt_kernel (same inputs/ops) -> dt_kernel and
// the svec round-trip are eliminated.
// Vectorization (r10): zt rows padded to 72 u16 (144B = 16B-aligned rows);
// staging u16x8; compute reads 4 rows x u16x8 (8 ds_read_b128/thread total
// vs 64 ds_read_u16 before); xs/cb writes u16x8. Tap math identical:
// out[l] = b + w.x*z[l-1] + w.y*z[l] + w.z*z[l+1] + w.w*z[l+2], silu.
// ot layout/stores and the OpT transpose loop are byte-identical to r9.
// ---------------------------------------------------------------------------
__global__ __launch_bounds__(256)
void conv_fused_kernel(const unsigned short* __restrict__ zxb,
                       const float* __restrict__ Wc,
                       const float* __restrict__ bc,
                       const float* __restrict__ dt_bias,
                       const float* __restrict__ A_log,
                       unsigned short* __restrict__ xs,
                       unsigned short* __restrict__ cb,
                       unsigned short* __restrict__ OpT) {
  __shared__ __align__(16) unsigned short zt[67][72];
  __shared__ unsigned short ot[64][66];
  __shared__ float sl[64];
  const int c0 = blockIdx.x * 64;
  const int l0 = blockIdx.y * 64;
  const int t = threadIdx.x;
  // stage 67 rows x 64 ch as u16x8 (8 per row)
  for (int idx = t; idx < 67 * 8; idx += 256) {
    int row = idx >> 3;
    int colh = (idx & 7) * 8;
    int gl = l0 - 1 + row;
    u16x8 v = (u16x8){0, 0, 0, 0, 0, 0, 0, 0};
    if (gl >= 0 && gl < L_SEQ)
      v = *(const u16x8*)&zxb[(size_t)gl * DPROJ + DI + c0 + colh];
    *(u16x8*)&zt[row][colh] = v;
  }
  const bool isX = (c0 < DI);
  const bool isC = (c0 >= DI + DS);
  // fused dt: sl[l] for this block's head (bit-identical to old dt_kernel)
  if (isX && t < 64) {
    int h = c0 >> 6;
    float v = bf2f(zxb[(size_t)(l0 + t) * DPROJ + (DI + CDIM) + h]) + dt_bias[h];
    float d = (v > 20.f) ? v : log1pf(expf(v));
    sl[t] = d * expf(-d * expf(A_log[h]));
  }
  const int lb = t & 31;            // l base; halves add 0/32
  const int cg = t >> 5;            // channel group of 8
  const int cbase = cg * 8;
  float4 wv[8];
  float bias[8];
#pragma unroll
  for (int j = 0; j < 8; ++j) {
    wv[j] = *(const float4*)&Wc[(c0 + cbase + j) * 4];
    bias[j] = bc[c0 + cbase + j];
  }
  __syncthreads();
#pragma unroll
  for (int half = 0; half < 2; ++half) {
    int ll = lb + half * 32;
    int gl = l0 + ll;
    u16x8 r0 = *(const u16x8*)&zt[ll][cbase];
    u16x8 r1 = *(const u16x8*)&zt[ll + 1][cbase];
    u16x8 r2 = *(const u16x8*)&zt[ll + 2][cbase];
    u16x8 r3 = *(const u16x8*)&zt[ll + 3][cbase];
    u16x8 vout;
#pragma unroll
    for (int j = 0; j < 8; ++j) {
      float sacc = bias[j] + bf2f(r0[j]) * wv[j].x + bf2f(r1[j]) * wv[j].y +
                   bf2f(r2[j]) * wv[j].z + bf2f(r3[j]) * wv[j].w;
      float v = sacc / (1.f + expf(-sacc));
      vout[j] = f2bf(v);
      if (isX)       ot[cbase + j][ll] = f2bf(v * sl[ll]);
      else if (!isC) ot[cbase + j][ll] = vout[j];
    }
    if (isC)
      *(u16x8*)&cb[(size_t)gl * DS + (c0 - (DI + DS)) + cbase] = vout;
    else if (isX)
      *(u16x8*)&xs[(size_t)gl * DI + c0 + cbase] = vout;
  }
  if (!isC) {
    __syncthreads();
#pragma unroll
    for (int j = 0; j < 4; ++j) {
      int linear = j * 1024 + t * 4;
      int rr = linear >> 6;
      int lc = linear & 63;
      *(u16x4*)&OpT[(size_t)(c0 + rr) * L_SEQ + l0 + lc] = *(const u16x4*)&ot[rr][lc];
    }
  }
}

// ---------------------------------------------------------------------------
// Ht[p][n] = bf16( sum_z Ppart[z][n][p] )
// ---------------------------------------------------------------------------
__global__ __launch_bounds__(256)
void h_reduce_t_kernel(const float* __restrict__ P, unsigned short* __restrict__ Ht) {
  __shared__ float tile[32][65];
  const int bid = blockIdx.x;
  const int pt = bid & 31, ng = bid >> 5;
  const int t = threadIdx.x;
#pragma unroll
  for (int i = 0; i < 8; ++i) {
    int nl = i * 4 + (t >> 6);
    int n = ng * 32 + nl;
    int p = pt * 64 + (t & 63);
    float acc = 0.f;
#pragma unroll
    for (int z = 0; z < KSPLIT; ++z)
      acc += P[(size_t)z * (DS * DI) + (size_t)n * DI + p];
    tile[nl][t & 63] = acc;
  }
  __syncthreads();
#pragma unroll
  for (int j = 0; j < 8; ++j) {
    int linear = j * 256 + t;
    int pl = linear >> 5, nl = linear & 31;
    Ht[(size_t)(pt * 64 + pl) * DS + ng * 32 + nl] = f2bf(tile[nl][pl]);
  }
}

// ---------------------------------------------------------------------------
// LayerNorm over 2048 (bf16 y) + z-gate (bf16 z); bf16 yz into zxb [2048,4096)
// ---------------------------------------------------------------------------
__global__ __launch_bounds__(256)
void ln_mul_kernel(const unsigned short* __restrict__ ybuf, unsigned short* __restrict__ zxb,
                   const float* __restrict__ ln_w, const float* __restrict__ ln_b) {
  int l = blockIdx.x;
  int t = threadIdx.x;
  int c0 = t * 8;
  u16x8 yv = *(const u16x8*)&ybuf[(size_t)l * DI + c0];
  float vals[8];
  float s = 0.f, sq = 0.f;
#pragma unroll
  for (int i = 0; i < 8; ++i) {
    float v = bf2f(yv[i]);
    vals[i] = v;
    s += v;
    sq += v * v;
  }
#pragma unroll
  for (int off = 32; off > 0; off >>= 1) {
    s += __shfl_down(s, off, 64);
    sq += __shfl_down(sq, off, 64);
  }
  __shared__ float red[10];
  int wave = t >> 6, lane = t & 63;
  if (lane == 0) { red[wave] = s; red[4 + wave] = sq; }
  __syncthreads();
  if (t == 0) {
    float S = red[0] + red[1] + red[2] + red[3];
    float SQ = red[4] + red[5] + red[6] + red[7];
    float mu = S / (float)DI;
    red[8] = mu;
    red[9] = rsqrtf(SQ / (float)DI - mu * mu + 1e-5f);
  }
  __syncthreads();
  float mu = red[8], rstd = red[9];
  unsigned short* zrow = zxb + (size_t)l * DPROJ;
  u16x8 zv = *(const u16x8*)&zrow[c0];
  float4 w0 = *(const float4*)&ln_w[c0], w1 = *(const float4*)&ln_w[c0 + 4];
  float4 b0 = *(const float4*)&ln_b[c0], b1 = *(const float4*)&ln_b[c0 + 4];
  float w[8] = {w0.x, w0.y, w0.z, w0.w, w1.x, w1.y, w1.z, w1.w};
  float b[8] = {b0.x, b0.y, b0.z, b0.w, b1.x, b1.y, b1.z, b1.w};
  u16x8 o;
#pragma unroll
  for (int i = 0; i < 8; ++i) {
    float v = (vals[i] - mu) * rstd * w[i] + b[i];
    o[i] = f2bf(v * bf2f(zv[i]));
  }
  *(u16x8*)&zrow[DI + c0] = o;
}

// ---------------------------------------------------------------------------
extern "C" void kernel_launch(void* const* d_in, const int* in_sizes, int n_in,
                              void* d_out, int out_size, void* d_ws, size_t ws_size,
                              hipStream_t stream) {
  const float* x       = (const float*)d_in[0];
  const float* W_in    = (const float*)d_in[1];
  const float* W_conv  = (const float*)d_in[2];
  const float* b_conv  = (const float*)d_in[3];
  const float* dt_bias = (const float*)d_in[4];
  const float* A_log   = (const float*)d_in[5];
  const float* D_param = (const float*)d_in[6];
  const float* ln_w    = (const float*)d_in[7];
  const float* ln_b    = (const float*)d_in[8];
  const float* W_out   = (const float*)d_in[9];
  float* out = (float*)d_out;

  // ---- workspace layout ----
  unsigned short* zxb = (unsigned short*)d_ws;           // L*4384 bf16
  unsigned short* xs   = zxb + (size_t)L_SEQ * DPROJ;    // L*2048 bf16
  unsigned short* cb   = xs + (size_t)L_SEQ * DI;        // L*128 bf16
  float* svec = (float*)(cb + (size_t)L_SEQ * DS);       // L*32 f32 (unused, layout keeper)
  unsigned short* OpT = (unsigned short*)(svec + (size_t)L_SEQ * NH);  // 2176*8192 bf16
  float* Ppart = (float*)(OpT + (size_t)OPROWS * L_SEQ); // KSPLIT*128*2048 f32
  unsigned short* Ht = (unsigned short*)(Ppart + (size_t)KSPLIT * DS * DI);  // 2048*128
  unsigned short* wout_bf16 = Ht + (size_t)DI * DS;      // 1024*2048 bf16
  // aliases in OpT's dead windows:
  unsigned short* x_bf16   = OpT;                        // casts..GEMM1 (16 MB)
  unsigned short* win_bf16 = OpT + (size_t)L_SEQ * DM;   // casts..GEMM1 (9.4 MB)
  unsigned short* ybuf     = OpT;                        // Y-GEMM..ln_mul (33.5 MB)

  // 0) all casts in one dispatch
  cast_all_kernel<<<14848, 256, 0, stream>>>(x, W_in, W_out, x_bf16, win_bf16,
                                             wout_bf16);

  // 1) zxb = bf16( x @ W_in^T )  (M=8192, N=4608 pad, K=1024)
  //    128x128 TLP (r5 structure, measured best); grid 36x64, 2 blocks/CU
  gemm128_tlp<0><<<dim3(NPAD_IN / 128, L_SEQ / 128), 512, 0, stream>>>(
      x_bf16, DM, win_bf16, DM, zxb, DPROJ, DM, DPROJ, nullptr, nullptr);

  // 2) conv + silu + transpose-pack + FUSED dt (clobbers x_bf16/win_bf16)
  conv_fused_kernel<<<dim3(CDIM / 64, L_SEQ / 64), 256, 0, stream>>>(
      zxb, W_conv, b_conv, dt_bias, A_log, xs, cb, OpT);

  // 3) Hcat = B^T @ Vs : M=128, N=2048, K=8192, split-K=16 (256 blocks, f32 out)
  gemm_bt_mfma<2><<<dim3(DI / 128, 1, KSPLIT), 256, 0, stream>>>(
      OpT + (size_t)DI * L_SEQ, L_SEQ, OpT, L_SEQ, Ppart, DI, L_SEQ, DI,
      nullptr, nullptr);

  // 4) reduce partials + transpose -> Ht (2048 x 128 bf16)
  h_reduce_t_kernel<<<128, 256, 0, stream>>>(Ppart, Ht);

  // 5) y = C @ Hcat + D*x_ssm : M=8192, N=2048, K=128 -> tlp OMODE 2
  gemm128_tlp<2><<<dim3(DI / 128, L_SEQ / 128), 512, 0, stream>>>(
      cb, DS, Ht, DS, ybuf, DI, DS, DI, xs, D_param);

  // 6) LN + z-gate -> bf16 yz into zxb cols [2048,4096)
  ln_mul_kernel<<<L_SEQ, 256, 0, stream>>>(ybuf, zxb, ln_w, ln_b);

  // 7) out = yz @ W_out^T : M=8192, N=1024, K=2048
  //    128x128 TLP f32 out: grid 8x64 = 512 blocks, 2 blocks/CU, 1 round
  gemm128_tlp<1><<<dim3(DM / 128, L_SEQ / 128), 512, 0, stream>>>(
      zxb + DI, DPROJ, wout_bf16, DI, out, DM, DI, DM, nullptr, nullptr);
}